// Round 4
// baseline (9769.805 us; speedup 1.0000x reference)
//
#include <hip/hip_runtime.h>
#include <stdint.h>
#include <stddef.h>

// ---------------- problem constants ----------------
#define kS 512
#define kB 64
#define kD 120
#define kOC 16
#define kKSZ 6
#define kPOOL 114
#define kLIN 1824   // 16*114
#define kH 1024
#define kG 4096
#define kO 48
#define kROWS (kS * kB)  // 32768
#define RNB 64           // recurrence blocks
#define FLAG_STRIDE 16   // ints -> 64B per flag slot

typedef __attribute__((ext_vector_type(8))) short bf16x8;
typedef __attribute__((ext_vector_type(4))) float f32x4;

__device__ __forceinline__ unsigned short f32_to_bf16(float f) {
  unsigned u = __float_as_uint(f);
  u += 0x7FFFu + ((u >> 16) & 1u);
  return (unsigned short)(u >> 16);
}
__device__ __forceinline__ float bf16_to_f32(unsigned short h) {
  return __uint_as_float(((unsigned)h) << 16);
}
__device__ __forceinline__ float sigmoid_(float x) { return 1.f / (1.f + __expf(-x)); }
__device__ __forceinline__ float tanh_(float x) { return 1.f - 2.f / (__expf(2.f * x) + 1.f); }

__device__ __forceinline__ void load_lds_16(const void* g, void* l) {
  __builtin_amdgcn_global_load_lds((__attribute__((address_space(1))) void*)g,
                                   (__attribute__((address_space(3))) void*)l, 16, 0, 0);
}

// ---------------- K0: weight conversion ----------------
__global__ void convert_weights(const float* __restrict__ wih, const float* __restrict__ whh,
                                const float* __restrict__ h2hw, const float* __restrict__ outw,
                                const float* __restrict__ bih, const float* __restrict__ bhh,
                                unsigned short* __restrict__ wihb, unsigned short* __restrict__ whhb,
                                unsigned short* __restrict__ h2hwb, unsigned short* __restrict__ outwb,
                                float* __restrict__ bsum) {
  const size_t N0 = (size_t)kG * kLIN;
  const size_t N1 = (size_t)kG * kH;
  const size_t N2 = (size_t)kH * kH;
  const size_t N3 = (size_t)kO * kH;
  const size_t N4 = kG;
  const size_t TOT = N0 + N1 + N2 + N3 + N4;
  for (size_t i = (size_t)blockIdx.x * blockDim.x + threadIdx.x; i < TOT;
       i += (size_t)gridDim.x * blockDim.x) {
    if (i < N0) wihb[i] = f32_to_bf16(wih[i]);
    else if (i < N0 + N1) whhb[i - N0] = f32_to_bf16(whh[i - N0]);
    else if (i < N0 + N1 + N2) h2hwb[i - N0 - N1] = f32_to_bf16(h2hw[i - N0 - N1]);
    else if (i < N0 + N1 + N2 + N3) outwb[i - N0 - N1 - N2] = f32_to_bf16(outw[i - N0 - N1 - N2]);
    else { size_t j = i - N0 - N1 - N2 - N3; bsum[j] = bih[j] + bhh[j]; }
  }
}

// ---------------- K1: conv1d + relu + maxpool -> feat bf16 (per-chunk) ----------------
__global__ __launch_bounds__(256) void conv_pool(const float* __restrict__ x,
                                                 const float* __restrict__ cw,
                                                 const float* __restrict__ cb,
                                                 unsigned short* __restrict__ feat,
                                                 long row_base) {
  __shared__ float xs[8][kD];
  __shared__ float ws[kOC][kKSZ];
  __shared__ float bs[kOC];
  const int tid = threadIdx.x;
  const long grow0 = row_base + (long)blockIdx.x * 8;
  const long lrow0 = (long)blockIdx.x * 8;
  if (tid < kOC * kKSZ) ws[tid / kKSZ][tid % kKSZ] = cw[tid];
  if (tid < kOC) bs[tid] = cb[tid];
  for (int i = tid; i < 8 * kD; i += 256) xs[i / kD][i % kD] = x[grow0 * kD + i];
  __syncthreads();
  for (int r = 0; r < 8; ++r) {
    for (int idx = tid; idx < kLIN; idx += 256) {
      const int oc = idx / kPOOL, p = idx % kPOOL;
      float c0 = bs[oc], c1 = bs[oc];
#pragma unroll
      for (int k = 0; k < kKSZ; ++k) {
        c0 += xs[r][p + k] * ws[oc][k];
        c1 += xs[r][p + 1 + k] * ws[oc][k];
      }
      float v = fmaxf(fmaxf(c0, c1), 0.f);
      feat[(lrow0 + r) * kLIN + idx] = f32_to_bf16(v);
    }
  }
}

// ---------------- K2/K4: 128x128 bf16 MFMA GEMM, C = act(A @ B^T + bias) ----------------
template <bool RELU>
__global__ __launch_bounds__(256) void gemm_bt_bf16(const unsigned short* __restrict__ A,
                                                    const unsigned short* __restrict__ B,
                                                    const float* __restrict__ bias,
                                                    unsigned short* __restrict__ C,
                                                    int N, int K) {
  __shared__ unsigned short Al[2][128 * 32];
  __shared__ unsigned short Bl[2][128 * 32];
  const int tid = threadIdx.x;
  const int lane = tid & 63;
  const int wid = tid >> 6;
  const int wm = wid >> 1, wn = wid & 1;
  const long bm = (long)blockIdx.x * 128;
  const long bn = (long)blockIdx.y * 128;
  const int NT = K / 32;

  f32x4 acc[4][4] = {};

  auto stage = [&](int buf, int kt) {
    const long k0 = (long)kt * 32;
#pragma unroll
    for (int rnd = 0; rnd < 2; ++rnd) {
      const int chunk = rnd * 256 + tid;  // 0..511
      const int r = chunk >> 2, c = chunk & 3;
      load_lds_16(A + (bm + r) * K + k0 + c * 8, &Al[buf][chunk * 8]);
      load_lds_16(B + (bn + r) * K + k0 + c * 8, &Bl[buf][chunk * 8]);
    }
  };

  stage(0, 0);
  __syncthreads();
  int buf = 0;
  for (int kt = 0; kt < NT; ++kt) {
    if (kt + 1 < NT) stage(buf ^ 1, kt + 1);
    bf16x8 af[4], bfr[4];
#pragma unroll
    for (int i = 0; i < 4; ++i) {
      const int ar = wm * 64 + i * 16 + (lane & 15);
      af[i] = *(const bf16x8*)&Al[buf][ar * 32 + (lane >> 4) * 8];
      const int bc = wn * 64 + i * 16 + (lane & 15);
      bfr[i] = *(const bf16x8*)&Bl[buf][bc * 32 + (lane >> 4) * 8];
    }
#pragma unroll
    for (int i = 0; i < 4; ++i)
#pragma unroll
      for (int j = 0; j < 4; ++j)
        acc[i][j] = __builtin_amdgcn_mfma_f32_16x16x32_bf16(af[i], bfr[j], acc[i][j], 0, 0, 0);
    __syncthreads();
    buf ^= 1;
  }

#pragma unroll
  for (int i = 0; i < 4; ++i) {
#pragma unroll
    for (int j = 0; j < 4; ++j) {
      const long col = bn + wn * 64 + j * 16 + (lane & 15);
      const float bv = bias[col];
#pragma unroll
      for (int e = 0; e < 4; ++e) {
        const long row = bm + wm * 64 + i * 16 + (lane >> 4) * 4 + e;
        float v = acc[i][j][e] + bv;
        if (RELU) v = fmaxf(v, 0.f);
        C[row * N + col] = f32_to_bf16(v);
      }
    }
  }
}

// ---------------- K3: persistent LSTM recurrence (per-chunk) ----------------
// 64 blocks x 256 thr, 1 block/CU (128KB LDS). Block owns 16 hidden units ->
// 64 gate cols, gate-major: col = g*16 + u so all 4 gates of unit u share lane.
// Barrier: parallel per-block flags (64B-padded slots, release store + 64-lane
// acquire poll) instead of a serialized atomic counter chain.
__global__ __launch_bounds__(256) void lstm_rec(const unsigned short* __restrict__ xw,
                                                const unsigned short* __restrict__ whh,
                                                const float* __restrict__ h0,
                                                const float* __restrict__ c0,
                                                float* __restrict__ cst,
                                                unsigned short* __restrict__ hbuf,
                                                unsigned short* __restrict__ hs,
                                                int* __restrict__ flags,
                                                int nsteps, int first, int barbase) {
  __shared__ unsigned short Bl[64 * 1024];  // 128 KB; short idx = kc*512 + col*8 + e
  const int tid = threadIdx.x;
  const int lane = tid & 63;
  const int w = tid >> 6;
  const int urow = lane & 15;
  const int bq = lane >> 4;
  const int u0 = blockIdx.x * 16;
  const int b0 = w * 16 + bq * 4;

  // stage W_hh slice (64 gate-cols x 1024 K) into LDS, k-tiled layout
  for (int idx = tid; idx < 64 * 128; idx += 256) {
    const int col = idx & 63;
    const int kc = idx >> 6;
    const int gcol = (col >> 4) * kH + u0 + (col & 15);
    *(bf16x8*)&Bl[kc * 512 + col * 8] = *(const bf16x8*)&whh[(long)gcol * kH + kc * 8];
  }
  float creg[4];
  if (first) {
    for (int i = tid; i < 1024; i += 256) {
      const int b = i >> 4, u = i & 15;
      hbuf[b * kH + u0 + u] = f32_to_bf16(h0[b * kH + u0 + u]);
    }
#pragma unroll
    for (int j = 0; j < 4; ++j) creg[j] = c0[(b0 + j) * kH + u0 + urow];
  } else {
#pragma unroll
    for (int j = 0; j < 4; ++j) creg[j] = cst[(b0 + j) * kH + u0 + urow];
  }

  // x-part of gates for step t (prefetched one step ahead)
  float xv[4][4];
  auto pf = [&](int t) {
#pragma unroll
    for (int j = 0; j < 4; ++j) {
      const unsigned short* xp = xw + (long)(t * kB + b0 + j) * kG + u0 + urow;
#pragma unroll
      for (int g = 0; g < 4; ++g) xv[j][g] = bf16_to_f32(xp[g * kH]);
    }
  };
  pf(0);

  // entry barrier (covers W staging visibility of h-init)
  __threadfence();
  __syncthreads();
  if (tid == 0)
    __hip_atomic_store(&flags[blockIdx.x * FLAG_STRIDE], barbase + 1, __ATOMIC_RELEASE,
                       __HIP_MEMORY_SCOPE_AGENT);
  if (tid < 64)
    while (__hip_atomic_load(&flags[tid * FLAG_STRIDE], __ATOMIC_ACQUIRE,
                             __HIP_MEMORY_SCOPE_AGENT) < barbase + 1)
      __builtin_amdgcn_s_sleep(1);
  __syncthreads();

  for (int t = 0; t < nsteps; ++t) {
    const unsigned short* cur = hbuf + (t & 1) * (kB * kH);
    unsigned short* nxt = hbuf + ((t + 1) & 1) * (kB * kH);

    f32x4 acc[4] = {};
    const unsigned short* arow = cur + (w * 16 + urow) * kH + bq * 8;
#pragma unroll 8
    for (int kt = 0; kt < 32; ++kt) {
      const bf16x8 a = *(const bf16x8*)(arow + kt * 32);
      const int kc = kt * 4 + bq;
#pragma unroll
      for (int g = 0; g < 4; ++g) {
        const bf16x8 bb = *(const bf16x8*)&Bl[kc * 512 + (g * 16 + urow) * 8];
        acc[g] = __builtin_amdgcn_mfma_f32_16x16x32_bf16(a, bb, acc[g], 0, 0, 0);
      }
    }

    float hv[4];
#pragma unroll
    for (int j = 0; j < 4; ++j) {
      const float gi = sigmoid_(acc[0][j] + xv[j][0]);
      const float gf = sigmoid_(acc[1][j] + xv[j][1]);
      const float gg = tanh_(acc[2][j] + xv[j][2]);
      const float go = sigmoid_(acc[3][j] + xv[j][3]);
      creg[j] = gf * creg[j] + gi * gg;
      hv[j] = go * tanh_(creg[j]);
      nxt[(b0 + j) * kH + u0 + urow] = f32_to_bf16(hv[j]);
    }

    // arrive: flush h stores, signal own flag (parallel lines, no RMW chain)
    __threadfence();
    __syncthreads();
    if (tid == 0)
      __hip_atomic_store(&flags[blockIdx.x * FLAG_STRIDE], barbase + t + 2, __ATOMIC_RELEASE,
                         __HIP_MEMORY_SCOPE_AGENT);

    // overlap with barrier propagation: hs relu-store (no cross-block reader
    // this step; kernel-end flush suffices) + next step's xw gather (HBM).
#pragma unroll
    for (int j = 0; j < 4; ++j)
      hs[(long)(t * kB + b0 + j) * kH + u0 + urow] = f32_to_bf16(fmaxf(hv[j], 0.f));
    if (t + 1 < nsteps) pf(t + 1);
#pragma unroll
    for (int j = 0; j < 4; ++j)
      asm volatile("" ::"v"(xv[j][0]), "v"(xv[j][1]), "v"(xv[j][2]), "v"(xv[j][3]));

    // wait: 64 lanes poll the 64 flags in parallel
    if (tid < 64)
      while (__hip_atomic_load(&flags[tid * FLAG_STRIDE], __ATOMIC_ACQUIRE,
                               __HIP_MEMORY_SCOPE_AGENT) < barbase + t + 2)
        __builtin_amdgcn_s_sleep(1);
    __syncthreads();
  }

#pragma unroll
  for (int j = 0; j < 4; ++j) cst[(b0 + j) * kH + u0 + urow] = creg[j];
}

// ---------------- K5: output head + log_softmax (per-chunk) ----------------
__global__ __launch_bounds__(256) void out_head(const unsigned short* __restrict__ h2,
                                                const unsigned short* __restrict__ ow,
                                                const float* __restrict__ ob,
                                                float* __restrict__ out) {
  __shared__ unsigned short Wl[48 * 1024];  // 96 KB; short idx = kc*384 + col*8 + e
  const int tid = threadIdx.x;
  const int lane = tid & 63;
  const int w = tid >> 6;
  for (int idx = tid; idx < 48 * 128; idx += 256) {
    const int col = idx % 48;
    const int kc = idx / 48;
    *(bf16x8*)&Wl[kc * 384 + col * 8] = *(const bf16x8*)&ow[(long)col * kH + kc * 8];
  }
  __syncthreads();
  const long row0 = (long)blockIdx.x * 64 + w * 16;
  f32x4 acc[3] = {};
  const unsigned short* arow = h2 + (row0 + (lane & 15)) * kH + (lane >> 4) * 8;
#pragma unroll 8
  for (int kt = 0; kt < 32; ++kt) {
    const bf16x8 a = *(const bf16x8*)(arow + kt * 32);
    const int kc = kt * 4 + (lane >> 4);
#pragma unroll
    for (int n = 0; n < 3; ++n) {
      const bf16x8 bb = *(const bf16x8*)&Wl[kc * 384 + (n * 16 + (lane & 15)) * 8];
      acc[n] = __builtin_amdgcn_mfma_f32_16x16x32_bf16(a, bb, acc[n], 0, 0, 0);
    }
  }
  const int colb = lane & 15;
#pragma unroll
  for (int j = 0; j < 4; ++j) {
    float v[3];
#pragma unroll
    for (int n = 0; n < 3; ++n) v[n] = acc[n][j] + ob[n * 16 + colb];
    float m = fmaxf(fmaxf(v[0], v[1]), v[2]);
#pragma unroll
    for (int s = 1; s < 16; s <<= 1) m = fmaxf(m, __shfl_xor(m, s, 64));
    float se = __expf(v[0] - m) + __expf(v[1] - m) + __expf(v[2] - m);
#pragma unroll
    for (int s = 1; s < 16; s <<= 1) se += __shfl_xor(se, s, 64);
    const float lse = m + __logf(se);
    const long row = row0 + (lane >> 4) * 4 + j;
#pragma unroll
    for (int n = 0; n < 3; ++n) out[row * 48 + n * 16 + colb] = v[n] - lse;
  }
}

// ---------------- host ----------------
extern "C" void kernel_launch(void* const* d_in, const int* in_sizes, int n_in,
                              void* d_out, int out_size, void* d_ws, size_t ws_size,
                              hipStream_t stream) {
  const float* input_ = (const float*)d_in[0];
  const float* hidden = (const float*)d_in[1];
  const float* cell = (const float*)d_in[2];
  const float* conv_w = (const float*)d_in[3];
  const float* conv_b = (const float*)d_in[4];
  const float* w_ih = (const float*)d_in[5];
  const float* w_hh = (const float*)d_in[6];
  const float* b_ih = (const float*)d_in[7];
  const float* b_hh = (const float*)d_in[8];
  const float* h2h_w = (const float*)d_in[9];
  const float* h2h_b = (const float*)d_in[10];
  const float* out_w = (const float*)d_in[11];
  const float* out_b = (const float*)d_in[12];
  float* out = (float*)d_out;

  // fixed (chunk-independent) footprint
  const size_t FIXED = ((size_t)kG * kLIN + (size_t)kG * kH + (size_t)kH * kH +
                        (size_t)kO * kH) * 2 +
                       (size_t)kG * 4 +
                       2 * (size_t)kB * kH * 2 +
                       (size_t)kB * kH * 4 +
                       8192 + 16 * 256;

  // largest chunk (timesteps) whose working set fits ws
  int CHUNK = 2;
  const int cand[] = {512, 256, 128, 64, 32, 16, 8, 4, 2};
  for (int i = 0; i < 9; ++i) {
    const size_t rowsC = (size_t)cand[i] * kB;
    const size_t need = FIXED + rowsC * (kLIN + kG) * 2;
    if (need <= ws_size) { CHUNK = cand[i]; break; }
  }
  const size_t rowsC = (size_t)CHUNK * kB;

  char* ws = (char*)d_ws;
  size_t off = 0;
  auto alloc = [&](size_t bytes) {
    char* p = ws + off;
    off += (bytes + 255) & ~(size_t)255;
    return p;
  };
  unsigned short* regionA = (unsigned short*)alloc(rowsC * kLIN * 2);
  unsigned short* regionB = (unsigned short*)alloc(rowsC * kG * 2);
  unsigned short* wih_b = (unsigned short*)alloc((size_t)kG * kLIN * 2);
  unsigned short* whh_b = (unsigned short*)alloc((size_t)kG * kH * 2);
  unsigned short* h2hw_b = (unsigned short*)alloc((size_t)kH * kH * 2);
  unsigned short* outw_b = (unsigned short*)alloc((size_t)kO * kH * 2);
  float* bias_sum = (float*)alloc((size_t)kG * 4);
  unsigned short* hbuf = (unsigned short*)alloc(2 * (size_t)kB * kH * 2);
  float* cstate = (float*)alloc((size_t)kB * kH * 4);
  int* flags = (int*)alloc(8192);

  unsigned short* feat_c = regionA;
  unsigned short* hs_c = regionA;   // feat dead after gemm<false>
  unsigned short* xw_c = regionB;
  unsigned short* h2_c = regionB;   // xw dead after lstm_rec

  hipMemsetAsync(flags, 0, 8192, stream);
  convert_weights<<<2048, 256, 0, stream>>>(w_ih, w_hh, h2h_w, out_w, b_ih, b_hh, wih_b, whh_b,
                                            h2hw_b, outw_b, bias_sum);

  const int nch = kS / CHUNK;
  for (int ci = 0; ci < nch; ++ci) {
    const long t0 = (long)ci * CHUNK;
    conv_pool<<<(int)(rowsC / 8), 256, 0, stream>>>(input_, conv_w, conv_b, feat_c, t0 * kB);
    gemm_bt_bf16<false><<<dim3((int)(rowsC / 128), kG / 128), 256, 0, stream>>>(
        feat_c, wih_b, bias_sum, xw_c, kG, kLIN);
    lstm_rec<<<RNB, 256, 0, stream>>>(xw_c, whh_b, hidden, cell, cstate, hbuf, hs_c, flags, CHUNK,
                                      ci == 0 ? 1 : 0, ci * (CHUNK + 1));
    gemm_bt_bf16<true><<<dim3((int)(rowsC / 128), kH / 128), 256, 0, stream>>>(
        hs_c, h2hw_b, h2h_b, h2_c, kH, kH);
    out_head<<<(int)(rowsC / 64), 256, 0, stream>>>(h2_c, outw_b, out_b, out + t0 * kB * kO);
  }
}

// Round 5
// 7377.406 us; speedup vs baseline: 1.3243x; 1.3243x over previous
//
#include <hip/hip_runtime.h>
#include <stdint.h>
#include <stddef.h>

// ---------------- problem constants ----------------
#define kS 512
#define kB 64
#define kD 120
#define kOC 16
#define kKSZ 6
#define kPOOL 114
#define kLIN 1824   // 16*114
#define kH 1024
#define kG 4096
#define kO 48
#define kROWS (kS * kB)  // 32768
#define RNB 64           // recurrence blocks

typedef __attribute__((ext_vector_type(8))) short bf16x8;
typedef __attribute__((ext_vector_type(4))) float f32x4;

__device__ __forceinline__ unsigned short f32_to_bf16(float f) {
  unsigned u = __float_as_uint(f);
  u += 0x7FFFu + ((u >> 16) & 1u);
  return (unsigned short)(u >> 16);
}
__device__ __forceinline__ float bf16_to_f32(unsigned short h) {
  return __uint_as_float(((unsigned)h) << 16);
}
__device__ __forceinline__ float sigmoid_(float x) { return 1.f / (1.f + __expf(-x)); }
__device__ __forceinline__ float tanh_(float x) { return 1.f - 2.f / (__expf(2.f * x) + 1.f); }

__device__ __forceinline__ void load_lds_16(const void* g, void* l) {
  __builtin_amdgcn_global_load_lds((__attribute__((address_space(1))) void*)g,
                                   (__attribute__((address_space(3))) void*)l, 16, 0, 0);
}

// ---------------- K0: weight conversion ----------------
__global__ void convert_weights(const float* __restrict__ wih, const float* __restrict__ whh,
                                const float* __restrict__ h2hw, const float* __restrict__ outw,
                                const float* __restrict__ bih, const float* __restrict__ bhh,
                                unsigned short* __restrict__ wihb, unsigned short* __restrict__ whhb,
                                unsigned short* __restrict__ h2hwb, unsigned short* __restrict__ outwb,
                                float* __restrict__ bsum) {
  const size_t N0 = (size_t)kG * kLIN;
  const size_t N1 = (size_t)kG * kH;
  const size_t N2 = (size_t)kH * kH;
  const size_t N3 = (size_t)kO * kH;
  const size_t N4 = kG;
  const size_t TOT = N0 + N1 + N2 + N3 + N4;
  for (size_t i = (size_t)blockIdx.x * blockDim.x + threadIdx.x; i < TOT;
       i += (size_t)gridDim.x * blockDim.x) {
    if (i < N0) wihb[i] = f32_to_bf16(wih[i]);
    else if (i < N0 + N1) whhb[i - N0] = f32_to_bf16(whh[i - N0]);
    else if (i < N0 + N1 + N2) h2hwb[i - N0 - N1] = f32_to_bf16(h2hw[i - N0 - N1]);
    else if (i < N0 + N1 + N2 + N3) outwb[i - N0 - N1 - N2] = f32_to_bf16(outw[i - N0 - N1 - N2]);
    else { size_t j = i - N0 - N1 - N2 - N3; bsum[j] = bih[j] + bhh[j]; }
  }
}

// ---------------- K1: conv1d + relu + maxpool -> feat bf16 (per-chunk) ----------------
__global__ __launch_bounds__(256) void conv_pool(const float* __restrict__ x,
                                                 const float* __restrict__ cw,
                                                 const float* __restrict__ cb,
                                                 unsigned short* __restrict__ feat,
                                                 long row_base) {
  __shared__ float xs[8][kD];
  __shared__ float ws[kOC][kKSZ];
  __shared__ float bs[kOC];
  const int tid = threadIdx.x;
  const long grow0 = row_base + (long)blockIdx.x * 8;
  const long lrow0 = (long)blockIdx.x * 8;
  if (tid < kOC * kKSZ) ws[tid / kKSZ][tid % kKSZ] = cw[tid];
  if (tid < kOC) bs[tid] = cb[tid];
  for (int i = tid; i < 8 * kD; i += 256) xs[i / kD][i % kD] = x[grow0 * kD + i];
  __syncthreads();
  for (int r = 0; r < 8; ++r) {
    for (int idx = tid; idx < kLIN; idx += 256) {
      const int oc = idx / kPOOL, p = idx % kPOOL;
      float c0 = bs[oc], c1 = bs[oc];
#pragma unroll
      for (int k = 0; k < kKSZ; ++k) {
        c0 += xs[r][p + k] * ws[oc][k];
        c1 += xs[r][p + 1 + k] * ws[oc][k];
      }
      float v = fmaxf(fmaxf(c0, c1), 0.f);
      feat[(lrow0 + r) * kLIN + idx] = f32_to_bf16(v);
    }
  }
}

// ---------------- K2/K4: 128x128 bf16 MFMA GEMM, C = act(A @ B^T + bias) ----------------
template <bool RELU>
__global__ __launch_bounds__(256) void gemm_bt_bf16(const unsigned short* __restrict__ A,
                                                    const unsigned short* __restrict__ B,
                                                    const float* __restrict__ bias,
                                                    unsigned short* __restrict__ C,
                                                    int N, int K) {
  __shared__ unsigned short Al[2][128 * 32];
  __shared__ unsigned short Bl[2][128 * 32];
  const int tid = threadIdx.x;
  const int lane = tid & 63;
  const int wid = tid >> 6;
  const int wm = wid >> 1, wn = wid & 1;
  const long bm = (long)blockIdx.x * 128;
  const long bn = (long)blockIdx.y * 128;
  const int NT = K / 32;

  f32x4 acc[4][4] = {};

  auto stage = [&](int buf, int kt) {
    const long k0 = (long)kt * 32;
#pragma unroll
    for (int rnd = 0; rnd < 2; ++rnd) {
      const int chunk = rnd * 256 + tid;  // 0..511
      const int r = chunk >> 2, c = chunk & 3;
      load_lds_16(A + (bm + r) * K + k0 + c * 8, &Al[buf][chunk * 8]);
      load_lds_16(B + (bn + r) * K + k0 + c * 8, &Bl[buf][chunk * 8]);
    }
  };

  stage(0, 0);
  __syncthreads();
  int buf = 0;
  for (int kt = 0; kt < NT; ++kt) {
    if (kt + 1 < NT) stage(buf ^ 1, kt + 1);
    bf16x8 af[4], bfr[4];
#pragma unroll
    for (int i = 0; i < 4; ++i) {
      const int ar = wm * 64 + i * 16 + (lane & 15);
      af[i] = *(const bf16x8*)&Al[buf][ar * 32 + (lane >> 4) * 8];
      const int bc = wn * 64 + i * 16 + (lane & 15);
      bfr[i] = *(const bf16x8*)&Bl[buf][bc * 32 + (lane >> 4) * 8];
    }
#pragma unroll
    for (int i = 0; i < 4; ++i)
#pragma unroll
      for (int j = 0; j < 4; ++j)
        acc[i][j] = __builtin_amdgcn_mfma_f32_16x16x32_bf16(af[i], bfr[j], acc[i][j], 0, 0, 0);
    __syncthreads();
    buf ^= 1;
  }

#pragma unroll
  for (int i = 0; i < 4; ++i) {
#pragma unroll
    for (int j = 0; j < 4; ++j) {
      const long col = bn + wn * 64 + j * 16 + (lane & 15);
      const float bv = bias[col];
#pragma unroll
      for (int e = 0; e < 4; ++e) {
        const long row = bm + wm * 64 + i * 16 + (lane >> 4) * 4 + e;
        float v = acc[i][j][e] + bv;
        if (RELU) v = fmaxf(v, 0.f);
        C[row * N + col] = f32_to_bf16(v);
      }
    }
  }
}

// ---------------- two-level grid barrier ----------------
// bar[g*16] g<8: group counters; bar[128]: master; bar[144]: generation.
// Arrival chain 8 parallel + 8 serial RMWs instead of 64 serial.
__device__ __forceinline__ void grid_barrier2(int* bar, int bid, int target) {
  __syncthreads();
  if (threadIdx.x == 0) {
    __threadfence();
    int* gcnt = &bar[(bid >> 3) * 16];
    const int p = __hip_atomic_fetch_add(gcnt, 1, __ATOMIC_ACQ_REL, __HIP_MEMORY_SCOPE_AGENT);
    if (p == target * 8 - 1) {
      const int pm =
          __hip_atomic_fetch_add(&bar[128], 1, __ATOMIC_ACQ_REL, __HIP_MEMORY_SCOPE_AGENT);
      if (pm == target * 8 - 1)
        __hip_atomic_store(&bar[144], target, __ATOMIC_RELEASE, __HIP_MEMORY_SCOPE_AGENT);
    }
    while (__hip_atomic_load(&bar[144], __ATOMIC_ACQUIRE, __HIP_MEMORY_SCOPE_AGENT) < target)
      __builtin_amdgcn_s_sleep(1);
    __threadfence();
  }
  __syncthreads();
}

// ---------------- K3: persistent LSTM recurrence (per-chunk) ----------------
// 64 blocks x 256 thr, 1 block/CU (128KB LDS). Block owns 16 hidden units ->
// 64 gate cols, gate-major: col = g*16 + u so all 4 gates of unit u share lane.
// h exchange layout is WRITER-major: hbuf[phase][writer][batch][16 units] so
// each block's per-step store is one contiguous 2KB burst (cheap L2 writeback).
// Reader: k-block of 8 units lies inside writer (k>>4)'s 32B row:
//   addr = (k>>4)*1024 + batch*16 + (k&15).
__global__ __launch_bounds__(256) void lstm_rec(const unsigned short* __restrict__ xw,
                                                const unsigned short* __restrict__ whh,
                                                const float* __restrict__ h0,
                                                const float* __restrict__ c0,
                                                float* __restrict__ cst,
                                                unsigned short* __restrict__ hbuf,
                                                unsigned short* __restrict__ hs,
                                                int* __restrict__ bar,
                                                int nsteps, int first, int barbase) {
  __shared__ unsigned short Bl[64 * 1024];  // 128 KB; short idx = kc*512 + col*8 + e
  const int tid = threadIdx.x;
  const int lane = tid & 63;
  const int w = tid >> 6;
  const int urow = lane & 15;
  const int bq = lane >> 4;
  const int bid = blockIdx.x;
  const int u0 = bid * 16;
  const int b0 = w * 16 + bq * 4;

  // stage W_hh slice (64 gate-cols x 1024 K) into LDS, k-tiled layout
  for (int idx = tid; idx < 64 * 128; idx += 256) {
    const int col = idx & 63;
    const int kc = idx >> 6;
    const int gcol = (col >> 4) * kH + u0 + (col & 15);
    *(bf16x8*)&Bl[kc * 512 + col * 8] = *(const bf16x8*)&whh[(long)gcol * kH + kc * 8];
  }
  float creg[4];
  if (first) {
    // init phase-0 h slice for this writer: [batch][16 units] contiguous
    for (int i = tid; i < 1024; i += 256) {
      const int b = i >> 4, u = i & 15;
      hbuf[bid * 1024 + b * 16 + u] = f32_to_bf16(h0[b * kH + u0 + u]);
    }
#pragma unroll
    for (int j = 0; j < 4; ++j) creg[j] = c0[(b0 + j) * kH + u0 + urow];
  } else {
#pragma unroll
    for (int j = 0; j < 4; ++j) creg[j] = cst[(b0 + j) * kH + u0 + urow];
  }

  grid_barrier2(bar, bid, barbase + 1);

  for (int t = 0; t < nsteps; ++t) {
    const unsigned short* cur = hbuf + (t & 1) * (RNB * 1024);
    unsigned short* nxt = hbuf + ((t + 1) & 1) * (RNB * 1024);

    // x-part of gates (HBM gather; latency hidden under the MFMA loop)
    float xv[4][4];
#pragma unroll
    for (int j = 0; j < 4; ++j) {
      const unsigned short* xp = xw + (long)(t * kB + b0 + j) * kG + u0 + urow;
#pragma unroll
      for (int g = 0; g < 4; ++g) xv[j][g] = bf16_to_f32(xp[g * kH]);
    }

    f32x4 acc[4] = {};
    const int abatch = w * 16 + urow;
#pragma unroll 8
    for (int kt = 0; kt < 32; ++kt) {
      // k0 = kt*32 + bq*8 -> writer = kt*2 + (bq>>1), unit offset (bq&1)*8
      const bf16x8 a =
          *(const bf16x8*)&cur[(kt * 2 + (bq >> 1)) * 1024 + abatch * 16 + (bq & 1) * 8];
      const int kc = kt * 4 + bq;
#pragma unroll
      for (int g = 0; g < 4; ++g) {
        const bf16x8 bb = *(const bf16x8*)&Bl[kc * 512 + (g * 16 + urow) * 8];
        acc[g] = __builtin_amdgcn_mfma_f32_16x16x32_bf16(a, bb, acc[g], 0, 0, 0);
      }
    }

#pragma unroll
    for (int j = 0; j < 4; ++j) {
      const float gi = sigmoid_(acc[0][j] + xv[j][0]);
      const float gf = sigmoid_(acc[1][j] + xv[j][1]);
      const float gg = tanh_(acc[2][j] + xv[j][2]);
      const float go = sigmoid_(acc[3][j] + xv[j][3]);
      creg[j] = gf * creg[j] + gi * gg;
      const float h = go * tanh_(creg[j]);
      nxt[bid * 1024 + (b0 + j) * 16 + urow] = f32_to_bf16(h);  // contiguous 2KB/block
      hs[(long)(t * kB + b0 + j) * kH + u0 + urow] = f32_to_bf16(fmaxf(h, 0.f));
    }
    grid_barrier2(bar, bid, barbase + t + 2);
  }

#pragma unroll
  for (int j = 0; j < 4; ++j) cst[(b0 + j) * kH + u0 + urow] = creg[j];
}

// ---------------- K5: output head + log_softmax (per-chunk) ----------------
__global__ __launch_bounds__(256) void out_head(const unsigned short* __restrict__ h2,
                                                const unsigned short* __restrict__ ow,
                                                const float* __restrict__ ob,
                                                float* __restrict__ out) {
  __shared__ unsigned short Wl[48 * 1024];  // 96 KB; short idx = kc*384 + col*8 + e
  const int tid = threadIdx.x;
  const int lane = tid & 63;
  const int w = tid >> 6;
  for (int idx = tid; idx < 48 * 128; idx += 256) {
    const int col = idx % 48;
    const int kc = idx / 48;
    *(bf16x8*)&Wl[kc * 384 + col * 8] = *(const bf16x8*)&ow[(long)col * kH + kc * 8];
  }
  __syncthreads();
  const long row0 = (long)blockIdx.x * 64 + w * 16;
  f32x4 acc[3] = {};
  const unsigned short* arow = h2 + (row0 + (lane & 15)) * kH + (lane >> 4) * 8;
#pragma unroll 8
  for (int kt = 0; kt < 32; ++kt) {
    const bf16x8 a = *(const bf16x8*)(arow + kt * 32);
    const int kc = kt * 4 + (lane >> 4);
#pragma unroll
    for (int n = 0; n < 3; ++n) {
      const bf16x8 bb = *(const bf16x8*)&Wl[kc * 384 + (n * 16 + (lane & 15)) * 8];
      acc[n] = __builtin_amdgcn_mfma_f32_16x16x32_bf16(a, bb, acc[n], 0, 0, 0);
    }
  }
  const int colb = lane & 15;
#pragma unroll
  for (int j = 0; j < 4; ++j) {
    float v[3];
#pragma unroll
    for (int n = 0; n < 3; ++n) v[n] = acc[n][j] + ob[n * 16 + colb];
    float m = fmaxf(fmaxf(v[0], v[1]), v[2]);
#pragma unroll
    for (int s = 1; s < 16; s <<= 1) m = fmaxf(m, __shfl_xor(m, s, 64));
    float se = __expf(v[0] - m) + __expf(v[1] - m) + __expf(v[2] - m);
#pragma unroll
    for (int s = 1; s < 16; s <<= 1) se += __shfl_xor(se, s, 64);
    const float lse = m + __logf(se);
    const long row = row0 + (lane >> 4) * 4 + j;
#pragma unroll
    for (int n = 0; n < 3; ++n) out[row * 48 + n * 16 + colb] = v[n] - lse;
  }
}

// ---------------- host ----------------
extern "C" void kernel_launch(void* const* d_in, const int* in_sizes, int n_in,
                              void* d_out, int out_size, void* d_ws, size_t ws_size,
                              hipStream_t stream) {
  const float* input_ = (const float*)d_in[0];
  const float* hidden = (const float*)d_in[1];
  const float* cell = (const float*)d_in[2];
  const float* conv_w = (const float*)d_in[3];
  const float* conv_b = (const float*)d_in[4];
  const float* w_ih = (const float*)d_in[5];
  const float* w_hh = (const float*)d_in[6];
  const float* b_ih = (const float*)d_in[7];
  const float* b_hh = (const float*)d_in[8];
  const float* h2h_w = (const float*)d_in[9];
  const float* h2h_b = (const float*)d_in[10];
  const float* out_w = (const float*)d_in[11];
  const float* out_b = (const float*)d_in[12];
  float* out = (float*)d_out;

  // fixed (chunk-independent) footprint
  const size_t FIXED = ((size_t)kG * kLIN + (size_t)kG * kH + (size_t)kH * kH +
                        (size_t)kO * kH) * 2 +
                       (size_t)kG * 4 +
                       2 * (size_t)kB * kH * 2 +
                       (size_t)kB * kH * 4 +
                       8192 + 16 * 256;

  // largest chunk (timesteps) whose working set fits ws
  int CHUNK = 2;
  const int cand[] = {512, 256, 128, 64, 32, 16, 8, 4, 2};
  for (int i = 0; i < 9; ++i) {
    const size_t rowsC = (size_t)cand[i] * kB;
    const size_t need = FIXED + rowsC * (kLIN + kG) * 2;
    if (need <= ws_size) { CHUNK = cand[i]; break; }
  }
  const size_t rowsC = (size_t)CHUNK * kB;

  char* ws = (char*)d_ws;
  size_t off = 0;
  auto alloc = [&](size_t bytes) {
    char* p = ws + off;
    off += (bytes + 255) & ~(size_t)255;
    return p;
  };
  unsigned short* regionA = (unsigned short*)alloc(rowsC * kLIN * 2);
  unsigned short* regionB = (unsigned short*)alloc(rowsC * kG * 2);
  unsigned short* wih_b = (unsigned short*)alloc((size_t)kG * kLIN * 2);
  unsigned short* whh_b = (unsigned short*)alloc((size_t)kG * kH * 2);
  unsigned short* h2hw_b = (unsigned short*)alloc((size_t)kH * kH * 2);
  unsigned short* outw_b = (unsigned short*)alloc((size_t)kO * kH * 2);
  float* bias_sum = (float*)alloc((size_t)kG * 4);
  unsigned short* hbuf = (unsigned short*)alloc(2 * (size_t)RNB * 1024 * 2);
  float* cstate = (float*)alloc((size_t)kB * kH * 4);
  int* bar = (int*)alloc(4096);

  unsigned short* feat_c = regionA;
  unsigned short* hs_c = regionA;   // feat dead after gemm<false>
  unsigned short* xw_c = regionB;
  unsigned short* h2_c = regionB;   // xw dead after lstm_rec

  hipMemsetAsync(bar, 0, 4096, stream);
  convert_weights<<<2048, 256, 0, stream>>>(w_ih, w_hh, h2h_w, out_w, b_ih, b_hh, wih_b, whh_b,
                                            h2hw_b, outw_b, bias_sum);

  const int nch = kS / CHUNK;
  for (int ci = 0; ci < nch; ++ci) {
    const long t0 = (long)ci * CHUNK;
    conv_pool<<<(int)(rowsC / 8), 256, 0, stream>>>(input_, conv_w, conv_b, feat_c, t0 * kB);
    gemm_bt_bf16<false><<<dim3((int)(rowsC / 128), kG / 128), 256, 0, stream>>>(
        feat_c, wih_b, bias_sum, xw_c, kG, kLIN);
    lstm_rec<<<RNB, 256, 0, stream>>>(xw_c, whh_b, hidden, cell, cstate, hbuf, hs_c, bar, CHUNK,
                                      ci == 0 ? 1 : 0, ci * (CHUNK + 1));
    gemm_bt_bf16<true><<<dim3((int)(rowsC / 128), kH / 128), 256, 0, stream>>>(
        hs_c, h2hw_b, h2h_b, h2_c, kH, kH);
    out_head<<<(int)(rowsC / 64), 256, 0, stream>>>(h2_c, outw_b, out_b, out + t0 * kB * kO);
  }
}

// Round 6
// 5874.614 us; speedup vs baseline: 1.6631x; 1.2558x over previous
//
#include <hip/hip_runtime.h>
#include <stdint.h>
#include <stddef.h>

// ---------------- problem constants ----------------
#define kS 512
#define kB 64
#define kD 120
#define kOC 16
#define kKSZ 6
#define kPOOL 114
#define kLIN 1824   // 16*114
#define kH 1024
#define kG 4096
#define kO 48
#define kROWS (kS * kB)  // 32768
#define RNB 64           // recurrence blocks
#define FLAG_STRIDE 16   // ints -> 64B per flag slot

typedef __attribute__((ext_vector_type(8))) short bf16x8;
typedef __attribute__((ext_vector_type(4))) float f32x4;

__device__ __forceinline__ unsigned short f32_to_bf16(float f) {
  unsigned u = __float_as_uint(f);
  u += 0x7FFFu + ((u >> 16) & 1u);
  return (unsigned short)(u >> 16);
}
__device__ __forceinline__ float bf16_to_f32(unsigned short h) {
  return __uint_as_float(((unsigned)h) << 16);
}
__device__ __forceinline__ float sigmoid_(float x) { return 1.f / (1.f + __expf(-x)); }
__device__ __forceinline__ float tanh_(float x) { return 1.f - 2.f / (__expf(2.f * x) + 1.f); }

__device__ __forceinline__ void load_lds_16(const void* g, void* l) {
  __builtin_amdgcn_global_load_lds((__attribute__((address_space(1))) void*)g,
                                   (__attribute__((address_space(3))) void*)l, 16, 0, 0);
}

// relaxed agent-scope 8B ops: plain sc-coherent loads/stores, NO wbl2/inv
__device__ __forceinline__ unsigned long long coh_load(const unsigned long long* p) {
  return __hip_atomic_load(p, __ATOMIC_RELAXED, __HIP_MEMORY_SCOPE_AGENT);
}
__device__ __forceinline__ void coh_store(unsigned long long* p, unsigned long long v) {
  __hip_atomic_store(p, v, __ATOMIC_RELAXED, __HIP_MEMORY_SCOPE_AGENT);
}

// ---------------- K0: weight conversion ----------------
__global__ void convert_weights(const float* __restrict__ wih, const float* __restrict__ whh,
                                const float* __restrict__ h2hw, const float* __restrict__ outw,
                                const float* __restrict__ bih, const float* __restrict__ bhh,
                                unsigned short* __restrict__ wihb, unsigned short* __restrict__ whhb,
                                unsigned short* __restrict__ h2hwb, unsigned short* __restrict__ outwb,
                                float* __restrict__ bsum) {
  const size_t N0 = (size_t)kG * kLIN;
  const size_t N1 = (size_t)kG * kH;
  const size_t N2 = (size_t)kH * kH;
  const size_t N3 = (size_t)kO * kH;
  const size_t N4 = kG;
  const size_t TOT = N0 + N1 + N2 + N3 + N4;
  for (size_t i = (size_t)blockIdx.x * blockDim.x + threadIdx.x; i < TOT;
       i += (size_t)gridDim.x * blockDim.x) {
    if (i < N0) wihb[i] = f32_to_bf16(wih[i]);
    else if (i < N0 + N1) whhb[i - N0] = f32_to_bf16(whh[i - N0]);
    else if (i < N0 + N1 + N2) h2hwb[i - N0 - N1] = f32_to_bf16(h2hw[i - N0 - N1]);
    else if (i < N0 + N1 + N2 + N3) outwb[i - N0 - N1 - N2] = f32_to_bf16(outw[i - N0 - N1 - N2]);
    else { size_t j = i - N0 - N1 - N2 - N3; bsum[j] = bih[j] + bhh[j]; }
  }
}

// ---------------- K1: conv1d + relu + maxpool -> feat bf16 (per-chunk) ----------------
__global__ __launch_bounds__(256) void conv_pool(const float* __restrict__ x,
                                                 const float* __restrict__ cw,
                                                 const float* __restrict__ cb,
                                                 unsigned short* __restrict__ feat,
                                                 long row_base) {
  __shared__ float xs[8][kD];
  __shared__ float ws[kOC][kKSZ];
  __shared__ float bs[kOC];
  const int tid = threadIdx.x;
  const long grow0 = row_base + (long)blockIdx.x * 8;
  const long lrow0 = (long)blockIdx.x * 8;
  if (tid < kOC * kKSZ) ws[tid / kKSZ][tid % kKSZ] = cw[tid];
  if (tid < kOC) bs[tid] = cb[tid];
  for (int i = tid; i < 8 * kD; i += 256) xs[i / kD][i % kD] = x[grow0 * kD + i];
  __syncthreads();
  for (int r = 0; r < 8; ++r) {
    for (int idx = tid; idx < kLIN; idx += 256) {
      const int oc = idx / kPOOL, p = idx % kPOOL;
      float c0 = bs[oc], c1 = bs[oc];
#pragma unroll
      for (int k = 0; k < kKSZ; ++k) {
        c0 += xs[r][p + k] * ws[oc][k];
        c1 += xs[r][p + 1 + k] * ws[oc][k];
      }
      float v = fmaxf(fmaxf(c0, c1), 0.f);
      feat[(lrow0 + r) * kLIN + idx] = f32_to_bf16(v);
    }
  }
}

// ---------------- K2/K4: 128x128 bf16 MFMA GEMM, C = act(A @ B^T + bias) ----------------
template <bool RELU>
__global__ __launch_bounds__(256) void gemm_bt_bf16(const unsigned short* __restrict__ A,
                                                    const unsigned short* __restrict__ B,
                                                    const float* __restrict__ bias,
                                                    unsigned short* __restrict__ C,
                                                    int N, int K) {
  __shared__ unsigned short Al[2][128 * 32];
  __shared__ unsigned short Bl[2][128 * 32];
  const int tid = threadIdx.x;
  const int lane = tid & 63;
  const int wid = tid >> 6;
  const int wm = wid >> 1, wn = wid & 1;
  const long bm = (long)blockIdx.x * 128;
  const long bn = (long)blockIdx.y * 128;
  const int NT = K / 32;

  f32x4 acc[4][4] = {};

  auto stage = [&](int buf, int kt) {
    const long k0 = (long)kt * 32;
#pragma unroll
    for (int rnd = 0; rnd < 2; ++rnd) {
      const int chunk = rnd * 256 + tid;  // 0..511
      const int r = chunk >> 2, c = chunk & 3;
      load_lds_16(A + (bm + r) * K + k0 + c * 8, &Al[buf][chunk * 8]);
      load_lds_16(B + (bn + r) * K + k0 + c * 8, &Bl[buf][chunk * 8]);
    }
  };

  stage(0, 0);
  __syncthreads();
  int buf = 0;
  for (int kt = 0; kt < NT; ++kt) {
    if (kt + 1 < NT) stage(buf ^ 1, kt + 1);
    bf16x8 af[4], bfr[4];
#pragma unroll
    for (int i = 0; i < 4; ++i) {
      const int ar = wm * 64 + i * 16 + (lane & 15);
      af[i] = *(const bf16x8*)&Al[buf][ar * 32 + (lane >> 4) * 8];
      const int bc = wn * 64 + i * 16 + (lane & 15);
      bfr[i] = *(const bf16x8*)&Bl[buf][bc * 32 + (lane >> 4) * 8];
    }
#pragma unroll
    for (int i = 0; i < 4; ++i)
#pragma unroll
      for (int j = 0; j < 4; ++j)
        acc[i][j] = __builtin_amdgcn_mfma_f32_16x16x32_bf16(af[i], bfr[j], acc[i][j], 0, 0, 0);
    __syncthreads();
    buf ^= 1;
  }

#pragma unroll
  for (int i = 0; i < 4; ++i) {
#pragma unroll
    for (int j = 0; j < 4; ++j) {
      const long col = bn + wn * 64 + j * 16 + (lane & 15);
      const float bv = bias[col];
#pragma unroll
      for (int e = 0; e < 4; ++e) {
        const long row = bm + wm * 64 + i * 16 + (lane >> 4) * 4 + e;
        float v = acc[i][j][e] + bv;
        if (RELU) v = fmaxf(v, 0.f);
        C[row * N + col] = f32_to_bf16(v);
      }
    }
  }
}

// ---------------- K3: persistent LSTM recurrence (per-chunk) ----------------
// 64 blocks x 256 thr, 1 block/CU (130KB LDS). Block owns 16 hidden units ->
// 64 gate cols, gate-major: col = g*16 + u (4 gates of unit u share lane).
// h exchange: hbuf[phase][writer][batch*4 + unit4] as 8B chunks, all accesses
// RELAXED agent-scope atomics (sc-coherent at LLC, no per-step L2 wb/inv).
// Barrier: per-block flag store + 64-lane relaxed poll; ordering = vmcnt drain
// at __syncthreads (sc stores retire at coherence point) + compiler fences.
__global__ __launch_bounds__(256) void lstm_rec(const unsigned short* __restrict__ xw,
                                                const unsigned short* __restrict__ whh,
                                                const float* __restrict__ h0,
                                                const float* __restrict__ c0,
                                                float* __restrict__ cst,
                                                unsigned long long* __restrict__ hbuf,
                                                unsigned short* __restrict__ hs,
                                                int* __restrict__ flags,
                                                int nsteps, int first, int barbase) {
  __shared__ unsigned short Bl[64 * 1024];   // 128 KB; idx = kc*512 + col*8 + e
  __shared__ unsigned long long hstage[256]; // 2 KB: this writer's [batch][16u] slice
  const int tid = threadIdx.x;
  const int lane = tid & 63;
  const int w = tid >> 6;
  const int urow = lane & 15;
  const int bq = lane >> 4;
  const int bid = blockIdx.x;
  const int u0 = bid * 16;
  const int b0 = w * 16 + bq * 4;

  // stage W_hh slice (64 gate-cols x 1024 K) into LDS, k-tiled layout
  for (int idx = tid; idx < 64 * 128; idx += 256) {
    const int col = idx & 63;
    const int kc = idx >> 6;
    const int gcol = (col >> 4) * kH + u0 + (col & 15);
    *(bf16x8*)&Bl[kc * 512 + col * 8] = *(const bf16x8*)&whh[(long)gcol * kH + kc * 8];
  }
  float creg[4];
  if (first) {
    // publish phase-0 h slice: thread tid owns 8B chunk tid (batch=tid>>2, 4 units)
    const int batch = tid >> 2, un4 = (tid & 3) * 4;
    unsigned long long v = 0;
#pragma unroll
    for (int e = 0; e < 4; ++e) {
      const unsigned long long b16 = f32_to_bf16(h0[batch * kH + u0 + un4 + e]);
      v |= b16 << (16 * e);
    }
    coh_store(&hbuf[(size_t)bid * 256 + tid], v);
#pragma unroll
    for (int j = 0; j < 4; ++j) creg[j] = c0[(b0 + j) * kH + u0 + urow];
  } else {
#pragma unroll
    for (int j = 0; j < 4; ++j) creg[j] = cst[(b0 + j) * kH + u0 + urow];
  }

  // entry barrier
  __syncthreads();  // drains this thread's vmem (incl. coh_store) before barrier
  asm volatile("" ::: "memory");
  if (tid == 0)
    __hip_atomic_store(&flags[bid * FLAG_STRIDE], barbase + 1, __ATOMIC_RELAXED,
                       __HIP_MEMORY_SCOPE_AGENT);
  if (tid < 64)
    while (__hip_atomic_load(&flags[tid * FLAG_STRIDE], __ATOMIC_RELAXED,
                             __HIP_MEMORY_SCOPE_AGENT) < barbase + 1)
      __builtin_amdgcn_s_sleep(1);
  asm volatile("" ::: "memory");
  __syncthreads();

  for (int t = 0; t < nsteps; ++t) {
    const unsigned long long* cur = hbuf + (size_t)(t & 1) * (RNB * 256);
    unsigned long long* nxt = hbuf + (size_t)((t + 1) & 1) * (RNB * 256);

    // x-part of gates (normal cached loads; hidden under MFMA loop)
    float xv[4][4];
#pragma unroll
    for (int j = 0; j < 4; ++j) {
      const unsigned short* xp = xw + (long)(t * kB + b0 + j) * kG + u0 + urow;
#pragma unroll
      for (int g = 0; g < 4; ++g) xv[j][g] = bf16_to_f32(xp[g * kH]);
    }

    f32x4 acc[4] = {};
    const int abatch = w * 16 + urow;
#pragma unroll 8
    for (int kt = 0; kt < 32; ++kt) {
      // k0 = kt*32 + bq*8 -> writer = kt*2 + (bq>>1); chunk = batch*4 + (bq&1)*2
      const unsigned long long* src =
          cur + (size_t)(kt * 2 + (bq >> 1)) * 256 + abatch * 4 + (bq & 1) * 2;
      union { unsigned long long q[2]; bf16x8 v; } a;
      a.q[0] = coh_load(src);
      a.q[1] = coh_load(src + 1);
      const int kc = kt * 4 + bq;
#pragma unroll
      for (int g = 0; g < 4; ++g) {
        const bf16x8 bb = *(const bf16x8*)&Bl[kc * 512 + (g * 16 + urow) * 8];
        acc[g] = __builtin_amdgcn_mfma_f32_16x16x32_bf16(a.v, bb, acc[g], 0, 0, 0);
      }
    }

    // gates -> h; stage into LDS so publish/hs are coalesced 8B stores
#pragma unroll
    for (int j = 0; j < 4; ++j) {
      const float gi = sigmoid_(acc[0][j] + xv[j][0]);
      const float gf = sigmoid_(acc[1][j] + xv[j][1]);
      const float gg = tanh_(acc[2][j] + xv[j][2]);
      const float go = sigmoid_(acc[3][j] + xv[j][3]);
      creg[j] = gf * creg[j] + gi * gg;
      ((unsigned short*)hstage)[(b0 + j) * 16 + urow] = f32_to_bf16(go * tanh_(creg[j]));
    }
    __syncthreads();  // hstage complete

    {
      const unsigned long long q = hstage[tid];
      coh_store(&nxt[(size_t)bid * 256 + tid], q);  // publish h (one 8B/thread)
      // relu'd copy to hs (bit-level relu on bf16), one coalesced 8B store
      unsigned long long r = 0;
#pragma unroll
      for (int e = 0; e < 4; ++e) {
        unsigned long long s = (q >> (16 * e)) & 0xFFFFull;
        if (s & 0x8000ull) s = 0;
        r |= s << (16 * e);
      }
      const int batch = tid >> 2, un4 = (tid & 3) * 4;
      *(unsigned long long*)&hs[(long)(t * kB + batch) * kH + u0 + un4] = r;
    }

    __syncthreads();  // per-thread vmcnt(0) drain: all sc-stores at LLC
    asm volatile("" ::: "memory");
    if (tid == 0)
      __hip_atomic_store(&flags[bid * FLAG_STRIDE], barbase + t + 2, __ATOMIC_RELAXED,
                         __HIP_MEMORY_SCOPE_AGENT);
    if (tid < 64)
      while (__hip_atomic_load(&flags[tid * FLAG_STRIDE], __ATOMIC_RELAXED,
                               __HIP_MEMORY_SCOPE_AGENT) < barbase + t + 2)
        __builtin_amdgcn_s_sleep(1);
    asm volatile("" ::: "memory");
    __syncthreads();
  }

#pragma unroll
  for (int j = 0; j < 4; ++j) cst[(b0 + j) * kH + u0 + urow] = creg[j];
}

// ---------------- K5: output head + log_softmax (per-chunk) ----------------
__global__ __launch_bounds__(256) void out_head(const unsigned short* __restrict__ h2,
                                                const unsigned short* __restrict__ ow,
                                                const float* __restrict__ ob,
                                                float* __restrict__ out) {
  __shared__ unsigned short Wl[48 * 1024];  // 96 KB; idx = kc*384 + col*8 + e
  const int tid = threadIdx.x;
  const int lane = tid & 63;
  const int w = tid >> 6;
  for (int idx = tid; idx < 48 * 128; idx += 256) {
    const int col = idx % 48;
    const int kc = idx / 48;
    *(bf16x8*)&Wl[kc * 384 + col * 8] = *(const bf16x8*)&ow[(long)col * kH + kc * 8];
  }
  __syncthreads();
  const long row0 = (long)blockIdx.x * 64 + w * 16;
  f32x4 acc[3] = {};
  const unsigned short* arow = h2 + (row0 + (lane & 15)) * kH + (lane >> 4) * 8;
#pragma unroll 8
  for (int kt = 0; kt < 32; ++kt) {
    const bf16x8 a = *(const bf16x8*)(arow + kt * 32);
    const int kc = kt * 4 + (lane >> 4);
#pragma unroll
    for (int n = 0; n < 3; ++n) {
      const bf16x8 bb = *(const bf16x8*)&Wl[kc * 384 + (n * 16 + (lane & 15)) * 8];
      acc[n] = __builtin_amdgcn_mfma_f32_16x16x32_bf16(a, bb, acc[n], 0, 0, 0);
    }
  }
  const int colb = lane & 15;
#pragma unroll
  for (int j = 0; j < 4; ++j) {
    float v[3];
#pragma unroll
    for (int n = 0; n < 3; ++n) v[n] = acc[n][j] + ob[n * 16 + colb];
    float m = fmaxf(fmaxf(v[0], v[1]), v[2]);
#pragma unroll
    for (int s = 1; s < 16; s <<= 1) m = fmaxf(m, __shfl_xor(m, s, 64));
    float se = __expf(v[0] - m) + __expf(v[1] - m) + __expf(v[2] - m);
#pragma unroll
    for (int s = 1; s < 16; s <<= 1) se += __shfl_xor(se, s, 64);
    const float lse = m + __logf(se);
    const long row = row0 + (lane >> 4) * 4 + j;
#pragma unroll
    for (int n = 0; n < 3; ++n) out[row * 48 + n * 16 + colb] = v[n] - lse;
  }
}

// ---------------- host ----------------
extern "C" void kernel_launch(void* const* d_in, const int* in_sizes, int n_in,
                              void* d_out, int out_size, void* d_ws, size_t ws_size,
                              hipStream_t stream) {
  const float* input_ = (const float*)d_in[0];
  const float* hidden = (const float*)d_in[1];
  const float* cell = (const float*)d_in[2];
  const float* conv_w = (const float*)d_in[3];
  const float* conv_b = (const float*)d_in[4];
  const float* w_ih = (const float*)d_in[5];
  const float* w_hh = (const float*)d_in[6];
  const float* b_ih = (const float*)d_in[7];
  const float* b_hh = (const float*)d_in[8];
  const float* h2h_w = (const float*)d_in[9];
  const float* h2h_b = (const float*)d_in[10];
  const float* out_w = (const float*)d_in[11];
  const float* out_b = (const float*)d_in[12];
  float* out = (float*)d_out;

  // fixed (chunk-independent) footprint
  const size_t FIXED = ((size_t)kG * kLIN + (size_t)kG * kH + (size_t)kH * kH +
                        (size_t)kO * kH) * 2 +
                       (size_t)kG * 4 +
                       2 * (size_t)RNB * 256 * 8 +   // hbuf 256KB
                       (size_t)kB * kH * 4 +
                       8192 + 16 * 256;

  // largest chunk (timesteps) whose working set fits ws
  int CHUNK = 2;
  const int cand[] = {512, 256, 128, 64, 32, 16, 8, 4, 2};
  for (int i = 0; i < 9; ++i) {
    const size_t rowsC = (size_t)cand[i] * kB;
    const size_t need = FIXED + rowsC * (kLIN + kG) * 2;
    if (need <= ws_size) { CHUNK = cand[i]; break; }
  }
  const size_t rowsC = (size_t)CHUNK * kB;

  char* ws = (char*)d_ws;
  size_t off = 0;
  auto alloc = [&](size_t bytes) {
    char* p = ws + off;
    off += (bytes + 255) & ~(size_t)255;
    return p;
  };
  unsigned short* regionA = (unsigned short*)alloc(rowsC * kLIN * 2);
  unsigned short* regionB = (unsigned short*)alloc(rowsC * kG * 2);
  unsigned short* wih_b = (unsigned short*)alloc((size_t)kG * kLIN * 2);
  unsigned short* whh_b = (unsigned short*)alloc((size_t)kG * kH * 2);
  unsigned short* h2hw_b = (unsigned short*)alloc((size_t)kH * kH * 2);
  unsigned short* outw_b = (unsigned short*)alloc((size_t)kO * kH * 2);
  float* bias_sum = (float*)alloc((size_t)kG * 4);
  unsigned long long* hbuf = (unsigned long long*)alloc(2 * (size_t)RNB * 256 * 8);
  float* cstate = (float*)alloc((size_t)kB * kH * 4);
  int* flags = (int*)alloc(8192);

  unsigned short* feat_c = regionA;
  unsigned short* hs_c = regionA;   // feat dead after gemm<false>
  unsigned short* xw_c = regionB;
  unsigned short* h2_c = regionB;   // xw dead after lstm_rec

  hipMemsetAsync(flags, 0, 8192, stream);
  convert_weights<<<2048, 256, 0, stream>>>(w_ih, w_hh, h2h_w, out_w, b_ih, b_hh, wih_b, whh_b,
                                            h2hw_b, outw_b, bias_sum);

  const int nch = kS / CHUNK;
  for (int ci = 0; ci < nch; ++ci) {
    const long t0 = (long)ci * CHUNK;
    conv_pool<<<(int)(rowsC / 8), 256, 0, stream>>>(input_, conv_w, conv_b, feat_c, t0 * kB);
    gemm_bt_bf16<false><<<dim3((int)(rowsC / 128), kG / 128), 256, 0, stream>>>(
        feat_c, wih_b, bias_sum, xw_c, kG, kLIN);
    lstm_rec<<<RNB, 256, 0, stream>>>(xw_c, whh_b, hidden, cell, cstate, hbuf, hs_c, flags, CHUNK,
                                      ci == 0 ? 1 : 0, ci * (CHUNK + 1));
    gemm_bt_bf16<true><<<dim3((int)(rowsC / 128), kH / 128), 256, 0, stream>>>(
        hs_c, h2hw_b, h2h_b, h2_c, kH, kH);
    out_head<<<(int)(rowsC / 64), 256, 0, stream>>>(h2_c, outw_b, out_b, out + t0 * kB * kO);
  }
}

// Round 7
// 4377.457 us; speedup vs baseline: 2.2318x; 1.3420x over previous
//
#include <hip/hip_runtime.h>
#include <stdint.h>
#include <stddef.h>

// ---------------- problem constants ----------------
#define kS 512
#define kB 64
#define kD 120
#define kOC 16
#define kKSZ 6
#define kPOOL 114
#define kLIN 1824   // 16*114
#define kH 1024
#define kG 4096
#define kO 48
#define kROWS (kS * kB)  // 32768
#define RNB 64           // recurrence blocks
#define FLAG_STRIDE 16   // ints -> 64B per flag slot

typedef __attribute__((ext_vector_type(8))) short bf16x8;
typedef __attribute__((ext_vector_type(4))) float f32x4;

__device__ __forceinline__ unsigned short f32_to_bf16(float f) {
  unsigned u = __float_as_uint(f);
  u += 0x7FFFu + ((u >> 16) & 1u);
  return (unsigned short)(u >> 16);
}
__device__ __forceinline__ float bf16_to_f32(unsigned short h) {
  return __uint_as_float(((unsigned)h) << 16);
}
__device__ __forceinline__ float sigmoid_(float x) { return 1.f / (1.f + __expf(-x)); }
__device__ __forceinline__ float tanh_(float x) { return 1.f - 2.f / (__expf(2.f * x) + 1.f); }

__device__ __forceinline__ void load_lds_16(const void* g, void* l) {
  __builtin_amdgcn_global_load_lds((__attribute__((address_space(1))) void*)g,
                                   (__attribute__((address_space(3))) void*)l, 16, 0, 0);
}

// relaxed agent-scope 8B ops: sc-coherent loads/stores at LLC, NO wbl2/inv
__device__ __forceinline__ unsigned long long coh_load(const unsigned long long* p) {
  return __hip_atomic_load(p, __ATOMIC_RELAXED, __HIP_MEMORY_SCOPE_AGENT);
}
__device__ __forceinline__ void coh_store(unsigned long long* p, unsigned long long v) {
  __hip_atomic_store(p, v, __ATOMIC_RELAXED, __HIP_MEMORY_SCOPE_AGENT);
}

// ---------------- K0: weight conversion ----------------
__global__ void convert_weights(const float* __restrict__ wih, const float* __restrict__ whh,
                                const float* __restrict__ h2hw, const float* __restrict__ outw,
                                const float* __restrict__ bih, const float* __restrict__ bhh,
                                unsigned short* __restrict__ wihb, unsigned short* __restrict__ whhb,
                                unsigned short* __restrict__ h2hwb, unsigned short* __restrict__ outwb,
                                float* __restrict__ bsum) {
  const size_t N0 = (size_t)kG * kLIN;
  const size_t N1 = (size_t)kG * kH;
  const size_t N2 = (size_t)kH * kH;
  const size_t N3 = (size_t)kO * kH;
  const size_t N4 = kG;
  const size_t TOT = N0 + N1 + N2 + N3 + N4;
  for (size_t i = (size_t)blockIdx.x * blockDim.x + threadIdx.x; i < TOT;
       i += (size_t)gridDim.x * blockDim.x) {
    if (i < N0) wihb[i] = f32_to_bf16(wih[i]);
    else if (i < N0 + N1) whhb[i - N0] = f32_to_bf16(whh[i - N0]);
    else if (i < N0 + N1 + N2) h2hwb[i - N0 - N1] = f32_to_bf16(h2hw[i - N0 - N1]);
    else if (i < N0 + N1 + N2 + N3) outwb[i - N0 - N1 - N2] = f32_to_bf16(outw[i - N0 - N1 - N2]);
    else { size_t j = i - N0 - N1 - N2 - N3; bsum[j] = bih[j] + bhh[j]; }
  }
}

// ---------------- K1: conv1d + relu + maxpool -> feat bf16 (per-chunk) ----------------
__global__ __launch_bounds__(256) void conv_pool(const float* __restrict__ x,
                                                 const float* __restrict__ cw,
                                                 const float* __restrict__ cb,
                                                 unsigned short* __restrict__ feat,
                                                 long row_base) {
  __shared__ float xs[8][kD];
  __shared__ float ws[kOC][kKSZ];
  __shared__ float bs[kOC];
  const int tid = threadIdx.x;
  const long grow0 = row_base + (long)blockIdx.x * 8;
  const long lrow0 = (long)blockIdx.x * 8;
  if (tid < kOC * kKSZ) ws[tid / kKSZ][tid % kKSZ] = cw[tid];
  if (tid < kOC) bs[tid] = cb[tid];
  for (int i = tid; i < 8 * kD; i += 256) xs[i / kD][i % kD] = x[grow0 * kD + i];
  __syncthreads();
  for (int r = 0; r < 8; ++r) {
    for (int idx = tid; idx < kLIN; idx += 256) {
      const int oc = idx / kPOOL, p = idx % kPOOL;
      float c0 = bs[oc], c1 = bs[oc];
#pragma unroll
      for (int k = 0; k < kKSZ; ++k) {
        c0 += xs[r][p + k] * ws[oc][k];
        c1 += xs[r][p + 1 + k] * ws[oc][k];
      }
      float v = fmaxf(fmaxf(c0, c1), 0.f);
      feat[(lrow0 + r) * kLIN + idx] = f32_to_bf16(v);
    }
  }
}

// ---------------- K2/K4: 128x128 bf16 MFMA GEMM ----------------
// MODE 0: C = A@B^T + bias (row-major). MODE 1: relu(...). MODE 2: no relu,
// C written in lstm-permuted layout: col=(g,bid,ur) -> ((row*64+bid)*64+g*16+ur)
template <int MODE>
__global__ __launch_bounds__(256) void gemm_bt_bf16(const unsigned short* __restrict__ A,
                                                    const unsigned short* __restrict__ B,
                                                    const float* __restrict__ bias,
                                                    unsigned short* __restrict__ C,
                                                    int N, int K) {
  __shared__ unsigned short Al[2][128 * 32];
  __shared__ unsigned short Bl[2][128 * 32];
  const int tid = threadIdx.x;
  const int lane = tid & 63;
  const int wid = tid >> 6;
  const int wm = wid >> 1, wn = wid & 1;
  const long bm = (long)blockIdx.x * 128;
  const long bn = (long)blockIdx.y * 128;
  const int NT = K / 32;

  f32x4 acc[4][4] = {};

  auto stage = [&](int buf, int kt) {
    const long k0 = (long)kt * 32;
#pragma unroll
    for (int rnd = 0; rnd < 2; ++rnd) {
      const int chunk = rnd * 256 + tid;  // 0..511
      const int r = chunk >> 2, c = chunk & 3;
      load_lds_16(A + (bm + r) * K + k0 + c * 8, &Al[buf][chunk * 8]);
      load_lds_16(B + (bn + r) * K + k0 + c * 8, &Bl[buf][chunk * 8]);
    }
  };

  stage(0, 0);
  __syncthreads();
  int buf = 0;
  for (int kt = 0; kt < NT; ++kt) {
    if (kt + 1 < NT) stage(buf ^ 1, kt + 1);
    bf16x8 af[4], bfr[4];
#pragma unroll
    for (int i = 0; i < 4; ++i) {
      const int ar = wm * 64 + i * 16 + (lane & 15);
      af[i] = *(const bf16x8*)&Al[buf][ar * 32 + (lane >> 4) * 8];
      const int bc = wn * 64 + i * 16 + (lane & 15);
      bfr[i] = *(const bf16x8*)&Bl[buf][bc * 32 + (lane >> 4) * 8];
    }
#pragma unroll
    for (int i = 0; i < 4; ++i)
#pragma unroll
      for (int j = 0; j < 4; ++j)
        acc[i][j] = __builtin_amdgcn_mfma_f32_16x16x32_bf16(af[i], bfr[j], acc[i][j], 0, 0, 0);
    __syncthreads();
    buf ^= 1;
  }

#pragma unroll
  for (int i = 0; i < 4; ++i) {
#pragma unroll
    for (int j = 0; j < 4; ++j) {
      const long col = bn + wn * 64 + j * 16 + (lane & 15);
      const float bv = bias[col];
#pragma unroll
      for (int e = 0; e < 4; ++e) {
        const long row = bm + wm * 64 + i * 16 + (lane >> 4) * 4 + e;
        float v = acc[i][j][e] + bv;
        if (MODE == 1) v = fmaxf(v, 0.f);
        if (MODE == 2) {
          const int g = (int)(col >> 10), b2 = (int)((col >> 4) & 63), ur = (int)(col & 15);
          C[(row * 64 + b2) * 64 + g * 16 + ur] = f32_to_bf16(v);
        } else {
          C[row * N + col] = f32_to_bf16(v);
        }
      }
    }
  }
}

// ---------------- K3: persistent LSTM recurrence (per-chunk) ----------------
// 64 blocks x 512 thr (8 waves = 2/SIMD), 1 block/CU (146KB LDS). Block owns
// 16 hidden units -> 64 gate cols (gate-major). K-SPLIT: waves 0-3 take
// k[0,512) (writers 0..31), waves 4-7 take k[512,1024) (writers 32..63);
// partials reduced via LDS. h exchange via RELAXED agent-scope 8B atomics
// (LLC-coherent, no L2 wb/inv). xw is PERMUTED: ((t*kB+b)*64+bid)*64+g*16+u.
__global__ __launch_bounds__(512) void lstm_rec(const unsigned short* __restrict__ xw,
                                                const unsigned short* __restrict__ whh,
                                                const float* __restrict__ h0,
                                                const float* __restrict__ c0,
                                                float* __restrict__ cst,
                                                unsigned long long* __restrict__ hbuf,
                                                unsigned short* __restrict__ hs,
                                                int* __restrict__ flags,
                                                int nsteps, int first, int barbase) {
  __shared__ unsigned short Bl[64 * 1024];   // 128 KB; idx = kc*512 + col*8 + e
  __shared__ unsigned long long hstage[256]; // 2 KB
  __shared__ f32x4 pacc[4][64][4];           // 16 KB partial acc (k-half 1)
  const int tid = threadIdx.x;
  const int lane = tid & 63;
  const int w = tid >> 6;
  const int khalf = w >> 2;  // 0: k[0,512), 1: k[512,1024)
  const int w4 = w & 3;
  const int urow = lane & 15;
  const int bq = lane >> 4;
  const int bid = blockIdx.x;
  const int u0 = bid * 16;
  const int b0 = w4 * 16 + bq * 4;

  // stage W_hh slice (64 gate-cols x 1024 K) into LDS, k-tiled layout
  for (int idx = tid; idx < 64 * 128; idx += 512) {
    const int col = idx & 63;
    const int kc = idx >> 6;
    const int gcol = (col >> 4) * kH + u0 + (col & 15);
    *(bf16x8*)&Bl[kc * 512 + col * 8] = *(const bf16x8*)&whh[(long)gcol * kH + kc * 8];
  }
  float creg[4];
  if (first) {
    if (tid < 256) {  // publish phase-0 h slice
      const int batch = tid >> 2, un4 = (tid & 3) * 4;
      unsigned long long v = 0;
#pragma unroll
      for (int e = 0; e < 4; ++e) {
        const unsigned long long b16 = f32_to_bf16(h0[batch * kH + u0 + un4 + e]);
        v |= b16 << (16 * e);
      }
      coh_store(&hbuf[(size_t)bid * 256 + tid], v);
    }
    if (khalf == 0)
#pragma unroll
      for (int j = 0; j < 4; ++j) creg[j] = c0[(b0 + j) * kH + u0 + urow];
  } else {
    if (khalf == 0)
#pragma unroll
      for (int j = 0; j < 4; ++j) creg[j] = cst[(b0 + j) * kH + u0 + urow];
  }

  // entry barrier
  __syncthreads();
  asm volatile("" ::: "memory");
  if (tid == 0)
    __hip_atomic_store(&flags[bid * FLAG_STRIDE], barbase + 1, __ATOMIC_RELAXED,
                       __HIP_MEMORY_SCOPE_AGENT);
  if (tid < 64)
    while (__hip_atomic_load(&flags[tid * FLAG_STRIDE], __ATOMIC_RELAXED,
                             __HIP_MEMORY_SCOPE_AGENT) < barbase + 1)
      __builtin_amdgcn_s_sleep(1);
  asm volatile("" ::: "memory");
  __syncthreads();

  for (int t = 0; t < nsteps; ++t) {
    const unsigned long long* cur = hbuf + (size_t)(t & 1) * (RNB * 256);
    unsigned long long* nxt = hbuf + (size_t)((t + 1) & 1) * (RNB * 256);

    // x-part of gates (permuted layout: dense 128B per (t,b) per block)
    float xv[4][4];
    if (khalf == 0) {
#pragma unroll
      for (int j = 0; j < 4; ++j) {
        const unsigned short* xp = xw + ((long)(t * kB + b0 + j) * 64 + bid) * 64 + urow;
#pragma unroll
        for (int g = 0; g < 4; ++g) xv[j][g] = bf16_to_f32(xp[g * 16]);
      }
    }

    f32x4 acc[4] = {};
    const int abatch = w4 * 16 + urow;
#pragma unroll 8
    for (int ktl = 0; ktl < 16; ++ktl) {
      const int kt = khalf * 16 + ktl;
      // k0 = kt*32 + bq*8 -> writer = kt*2 + (bq>>1); chunk = batch*4 + (bq&1)*2
      const unsigned long long* src =
          cur + (size_t)(kt * 2 + (bq >> 1)) * 256 + abatch * 4 + (bq & 1) * 2;
      union { unsigned long long q[2]; bf16x8 v; } a;
      a.q[0] = coh_load(src);
      a.q[1] = coh_load(src + 1);
      const int kc = kt * 4 + bq;
#pragma unroll
      for (int g = 0; g < 4; ++g) {
        const bf16x8 bb = *(const bf16x8*)&Bl[kc * 512 + (g * 16 + urow) * 8];
        acc[g] = __builtin_amdgcn_mfma_f32_16x16x32_bf16(a.v, bb, acc[g], 0, 0, 0);
      }
    }

    if (khalf == 1) {
#pragma unroll
      for (int g = 0; g < 4; ++g) pacc[w4][lane][g] = acc[g];
    }
    __syncthreads();  // partials ready

    if (khalf == 0) {
#pragma unroll
      for (int j = 0; j < 4; ++j) {
        const float s0 = acc[0][j] + pacc[w4][lane][0][j] + xv[j][0];
        const float s1 = acc[1][j] + pacc[w4][lane][1][j] + xv[j][1];
        const float s2 = acc[2][j] + pacc[w4][lane][2][j] + xv[j][2];
        const float s3 = acc[3][j] + pacc[w4][lane][3][j] + xv[j][3];
        const float gi = sigmoid_(s0);
        const float gf = sigmoid_(s1);
        const float gg = tanh_(s2);
        const float go = sigmoid_(s3);
        creg[j] = gf * creg[j] + gi * gg;
        ((unsigned short*)hstage)[(b0 + j) * 16 + urow] = f32_to_bf16(go * tanh_(creg[j]));
      }
    }
    __syncthreads();  // hstage complete

    unsigned long long q = 0;
    if (tid < 256) {
      q = hstage[tid];
      coh_store(&nxt[(size_t)bid * 256 + tid], q);  // publish h (one 8B/thread)
    }

    __syncthreads();  // per-thread vmcnt drain: publish stores at LLC
    asm volatile("" ::: "memory");
    if (tid == 0)
      __hip_atomic_store(&flags[bid * FLAG_STRIDE], barbase + t + 2, __ATOMIC_RELAXED,
                         __HIP_MEMORY_SCOPE_AGENT);

    // hs relu-store overlaps barrier propagation (no cross-block reader)
    if (tid < 256) {
      unsigned long long r = 0;
#pragma unroll
      for (int e = 0; e < 4; ++e) {
        unsigned long long s = (q >> (16 * e)) & 0xFFFFull;
        if (s & 0x8000ull) s = 0;
        r |= s << (16 * e);
      }
      const int batch = tid >> 2, un4 = (tid & 3) * 4;
      *(unsigned long long*)&hs[(long)(t * kB + batch) * kH + u0 + un4] = r;
    }

    if (tid < 64)
      while (__hip_atomic_load(&flags[tid * FLAG_STRIDE], __ATOMIC_RELAXED,
                               __HIP_MEMORY_SCOPE_AGENT) < barbase + t + 2)
        __builtin_amdgcn_s_sleep(1);
    asm volatile("" ::: "memory");
    __syncthreads();
  }

  if (khalf == 0)
#pragma unroll
    for (int j = 0; j < 4; ++j) cst[(b0 + j) * kH + u0 + urow] = creg[j];
}

// ---------------- K5: output head + log_softmax (per-chunk) ----------------
__global__ __launch_bounds__(256) void out_head(const unsigned short* __restrict__ h2,
                                                const unsigned short* __restrict__ ow,
                                                const float* __restrict__ ob,
                                                float* __restrict__ out) {
  __shared__ unsigned short Wl[48 * 1024];  // 96 KB; idx = kc*384 + col*8 + e
  const int tid = threadIdx.x;
  const int lane = tid & 63;
  const int w = tid >> 6;
  for (int idx = tid; idx < 48 * 128; idx += 256) {
    const int col = idx % 48;
    const int kc = idx / 48;
    *(bf16x8*)&Wl[kc * 384 + col * 8] = *(const bf16x8*)&ow[(long)col * kH + kc * 8];
  }
  __syncthreads();
  const long row0 = (long)blockIdx.x * 64 + w * 16;
  f32x4 acc[3] = {};
  const unsigned short* arow = h2 + (row0 + (lane & 15)) * kH + (lane >> 4) * 8;
#pragma unroll 8
  for (int kt = 0; kt < 32; ++kt) {
    const bf16x8 a = *(const bf16x8*)(arow + kt * 32);
    const int kc = kt * 4 + (lane >> 4);
#pragma unroll
    for (int n = 0; n < 3; ++n) {
      const bf16x8 bb = *(const bf16x8*)&Wl[kc * 384 + (n * 16 + (lane & 15)) * 8];
      acc[n] = __builtin_amdgcn_mfma_f32_16x16x32_bf16(a, bb, acc[n], 0, 0, 0);
    }
  }
  const int colb = lane & 15;
#pragma unroll
  for (int j = 0; j < 4; ++j) {
    float v[3];
#pragma unroll
    for (int n = 0; n < 3; ++n) v[n] = acc[n][j] + ob[n * 16 + colb];
    float m = fmaxf(fmaxf(v[0], v[1]), v[2]);
#pragma unroll
    for (int s = 1; s < 16; s <<= 1) m = fmaxf(m, __shfl_xor(m, s, 64));
    float se = __expf(v[0] - m) + __expf(v[1] - m) + __expf(v[2] - m);
#pragma unroll
    for (int s = 1; s < 16; s <<= 1) se += __shfl_xor(se, s, 64);
    const float lse = m + __logf(se);
    const long row = row0 + (lane >> 4) * 4 + j;
#pragma unroll
    for (int n = 0; n < 3; ++n) out[row * 48 + n * 16 + colb] = v[n] - lse;
  }
}

// ---------------- host ----------------
extern "C" void kernel_launch(void* const* d_in, const int* in_sizes, int n_in,
                              void* d_out, int out_size, void* d_ws, size_t ws_size,
                              hipStream_t stream) {
  const float* input_ = (const float*)d_in[0];
  const float* hidden = (const float*)d_in[1];
  const float* cell = (const float*)d_in[2];
  const float* conv_w = (const float*)d_in[3];
  const float* conv_b = (const float*)d_in[4];
  const float* w_ih = (const float*)d_in[5];
  const float* w_hh = (const float*)d_in[6];
  const float* b_ih = (const float*)d_in[7];
  const float* b_hh = (const float*)d_in[8];
  const float* h2h_w = (const float*)d_in[9];
  const float* h2h_b = (const float*)d_in[10];
  const float* out_w = (const float*)d_in[11];
  const float* out_b = (const float*)d_in[12];
  float* out = (float*)d_out;

  // fixed (chunk-independent) footprint
  const size_t FIXED = ((size_t)kG * kLIN + (size_t)kG * kH + (size_t)kH * kH +
                        (size_t)kO * kH) * 2 +
                       (size_t)kG * 4 +
                       2 * (size_t)RNB * 256 * 8 +   // hbuf 256KB
                       (size_t)kB * kH * 4 +
                       8192 + 16 * 256;

  // largest chunk (timesteps) whose working set fits ws
  int CHUNK = 2;
  const int cand[] = {512, 256, 128, 64, 32, 16, 8, 4, 2};
  for (int i = 0; i < 9; ++i) {
    const size_t rowsC = (size_t)cand[i] * kB;
    const size_t need = FIXED + rowsC * (kLIN + kG) * 2;
    if (need <= ws_size) { CHUNK = cand[i]; break; }
  }
  const size_t rowsC = (size_t)CHUNK * kB;

  char* ws = (char*)d_ws;
  size_t off = 0;
  auto alloc = [&](size_t bytes) {
    char* p = ws + off;
    off += (bytes + 255) & ~(size_t)255;
    return p;
  };
  unsigned short* regionA = (unsigned short*)alloc(rowsC * kLIN * 2);
  unsigned short* regionB = (unsigned short*)alloc(rowsC * kG * 2);
  unsigned short* wih_b = (unsigned short*)alloc((size_t)kG * kLIN * 2);
  unsigned short* whh_b = (unsigned short*)alloc((size_t)kG * kH * 2);
  unsigned short* h2hw_b = (unsigned short*)alloc((size_t)kH * kH * 2);
  unsigned short* outw_b = (unsigned short*)alloc((size_t)kO * kH * 2);
  float* bias_sum = (float*)alloc((size_t)kG * 4);
  unsigned long long* hbuf = (unsigned long long*)alloc(2 * (size_t)RNB * 256 * 8);
  float* cstate = (float*)alloc((size_t)kB * kH * 4);
  int* flags = (int*)alloc(8192);

  unsigned short* feat_c = regionA;
  unsigned short* hs_c = regionA;   // feat dead after gemm<2>
  unsigned short* xw_c = regionB;
  unsigned short* h2_c = regionB;   // xw dead after lstm_rec

  hipMemsetAsync(flags, 0, 8192, stream);
  convert_weights<<<2048, 256, 0, stream>>>(w_ih, w_hh, h2h_w, out_w, b_ih, b_hh, wih_b, whh_b,
                                            h2hw_b, outw_b, bias_sum);

  const int nch = kS / CHUNK;
  for (int ci = 0; ci < nch; ++ci) {
    const long t0 = (long)ci * CHUNK;
    conv_pool<<<(int)(rowsC / 8), 256, 0, stream>>>(input_, conv_w, conv_b, feat_c, t0 * kB);
    gemm_bt_bf16<2><<<dim3((int)(rowsC / 128), kG / 128), 256, 0, stream>>>(
        feat_c, wih_b, bias_sum, xw_c, kG, kLIN);
    lstm_rec<<<RNB, 512, 0, stream>>>(xw_c, whh_b, hidden, cell, cstate, hbuf, hs_c, flags, CHUNK,
                                      ci == 0 ? 1 : 0, ci * (CHUNK + 1));
    gemm_bt_bf16<1><<<dim3((int)(rowsC / 128), kH / 128), 256, 0, stream>>>(
        hs_c, h2hw_b, h2h_b, h2_c, kH, kH);
    out_head<<<(int)(rowsC / 64), 256, 0, stream>>>(h2_c, outw_b, out_b, out + t0 * kB * kO);
  }
}

// Round 8
// 3454.676 us; speedup vs baseline: 2.8280x; 1.2671x over previous
//
#include <hip/hip_runtime.h>
#include <stdint.h>
#include <stddef.h>

// ---------------- problem constants ----------------
#define kS 512
#define kB 64
#define kD 120
#define kOC 16
#define kKSZ 6
#define kPOOL 114
#define kLIN 1824   // 16*114
#define kH 1024
#define kG 4096
#define kO 48
#define kROWS (kS * kB)  // 32768
#define RNB 128          // recurrence blocks: 64 unit-slices x 2 batch-halves
#define FLAG_STRIDE 16   // ints -> 64B per flag slot

typedef __attribute__((ext_vector_type(8))) short bf16x8;
typedef __attribute__((ext_vector_type(4))) float f32x4;

__device__ __forceinline__ unsigned short f32_to_bf16(float f) {
  unsigned u = __float_as_uint(f);
  u += 0x7FFFu + ((u >> 16) & 1u);
  return (unsigned short)(u >> 16);
}
__device__ __forceinline__ float bf16_to_f32(unsigned short h) {
  return __uint_as_float(((unsigned)h) << 16);
}
__device__ __forceinline__ float sigmoid_(float x) { return 1.f / (1.f + __expf(-x)); }
__device__ __forceinline__ float tanh_(float x) { return 1.f - 2.f / (__expf(2.f * x) + 1.f); }

__device__ __forceinline__ void load_lds_16(const void* g, void* l) {
  __builtin_amdgcn_global_load_lds((__attribute__((address_space(1))) void*)g,
                                   (__attribute__((address_space(3))) void*)l, 16, 0, 0);
}

// relaxed agent-scope 8B ops: sc-coherent loads/stores at LLC, NO wbl2/inv
__device__ __forceinline__ unsigned long long coh_load(const unsigned long long* p) {
  return __hip_atomic_load(p, __ATOMIC_RELAXED, __HIP_MEMORY_SCOPE_AGENT);
}
__device__ __forceinline__ void coh_store(unsigned long long* p, unsigned long long v) {
  __hip_atomic_store(p, v, __ATOMIC_RELAXED, __HIP_MEMORY_SCOPE_AGENT);
}

// ---------------- K0: weight conversion ----------------
__global__ void convert_weights(const float* __restrict__ wih, const float* __restrict__ whh,
                                const float* __restrict__ h2hw, const float* __restrict__ outw,
                                const float* __restrict__ bih, const float* __restrict__ bhh,
                                unsigned short* __restrict__ wihb, unsigned short* __restrict__ whhb,
                                unsigned short* __restrict__ h2hwb, unsigned short* __restrict__ outwb,
                                float* __restrict__ bsum) {
  const size_t N0 = (size_t)kG * kLIN;
  const size_t N1 = (size_t)kG * kH;
  const size_t N2 = (size_t)kH * kH;
  const size_t N3 = (size_t)kO * kH;
  const size_t N4 = kG;
  const size_t TOT = N0 + N1 + N2 + N3 + N4;
  for (size_t i = (size_t)blockIdx.x * blockDim.x + threadIdx.x; i < TOT;
       i += (size_t)gridDim.x * blockDim.x) {
    if (i < N0) wihb[i] = f32_to_bf16(wih[i]);
    else if (i < N0 + N1) whhb[i - N0] = f32_to_bf16(whh[i - N0]);
    else if (i < N0 + N1 + N2) h2hwb[i - N0 - N1] = f32_to_bf16(h2hw[i - N0 - N1]);
    else if (i < N0 + N1 + N2 + N3) outwb[i - N0 - N1 - N2] = f32_to_bf16(outw[i - N0 - N1 - N2]);
    else { size_t j = i - N0 - N1 - N2 - N3; bsum[j] = bih[j] + bhh[j]; }
  }
}

// ---------------- K1: conv1d + relu + maxpool -> feat bf16 (per-chunk) ----------------
__global__ __launch_bounds__(256) void conv_pool(const float* __restrict__ x,
                                                 const float* __restrict__ cw,
                                                 const float* __restrict__ cb,
                                                 unsigned short* __restrict__ feat,
                                                 long row_base) {
  __shared__ float xs[8][kD];
  __shared__ float ws[kOC][kKSZ];
  __shared__ float bs[kOC];
  const int tid = threadIdx.x;
  const long grow0 = row_base + (long)blockIdx.x * 8;
  const long lrow0 = (long)blockIdx.x * 8;
  if (tid < kOC * kKSZ) ws[tid / kKSZ][tid % kKSZ] = cw[tid];
  if (tid < kOC) bs[tid] = cb[tid];
  for (int i = tid; i < 8 * kD; i += 256) xs[i / kD][i % kD] = x[grow0 * kD + i];
  __syncthreads();
  for (int r = 0; r < 8; ++r) {
    for (int idx = tid; idx < kLIN; idx += 256) {
      const int oc = idx / kPOOL, p = idx % kPOOL;
      float c0 = bs[oc], c1 = bs[oc];
#pragma unroll
      for (int k = 0; k < kKSZ; ++k) {
        c0 += xs[r][p + k] * ws[oc][k];
        c1 += xs[r][p + 1 + k] * ws[oc][k];
      }
      float v = fmaxf(fmaxf(c0, c1), 0.f);
      feat[(lrow0 + r) * kLIN + idx] = f32_to_bf16(v);
    }
  }
}

// ---------------- K2/K4: 128x128 bf16 MFMA GEMM ----------------
// MODE 0: C = A@B^T + bias (row-major). MODE 1: relu(...). MODE 2: no relu,
// C written in lstm-permuted layout: col=(g,ublk,ur) -> ((row*64+ublk)*64+g*16+ur)
template <int MODE>
__global__ __launch_bounds__(256) void gemm_bt_bf16(const unsigned short* __restrict__ A,
                                                    const unsigned short* __restrict__ B,
                                                    const float* __restrict__ bias,
                                                    unsigned short* __restrict__ C,
                                                    int N, int K) {
  __shared__ unsigned short Al[2][128 * 32];
  __shared__ unsigned short Bl[2][128 * 32];
  const int tid = threadIdx.x;
  const int lane = tid & 63;
  const int wid = tid >> 6;
  const int wm = wid >> 1, wn = wid & 1;
  const long bm = (long)blockIdx.x * 128;
  const long bn = (long)blockIdx.y * 128;
  const int NT = K / 32;

  f32x4 acc[4][4] = {};

  auto stage = [&](int buf, int kt) {
    const long k0 = (long)kt * 32;
#pragma unroll
    for (int rnd = 0; rnd < 2; ++rnd) {
      const int chunk = rnd * 256 + tid;  // 0..511
      const int r = chunk >> 2, c = chunk & 3;
      load_lds_16(A + (bm + r) * K + k0 + c * 8, &Al[buf][chunk * 8]);
      load_lds_16(B + (bn + r) * K + k0 + c * 8, &Bl[buf][chunk * 8]);
    }
  };

  stage(0, 0);
  __syncthreads();
  int buf = 0;
  for (int kt = 0; kt < NT; ++kt) {
    if (kt + 1 < NT) stage(buf ^ 1, kt + 1);
    bf16x8 af[4], bfr[4];
#pragma unroll
    for (int i = 0; i < 4; ++i) {
      const int ar = wm * 64 + i * 16 + (lane & 15);
      af[i] = *(const bf16x8*)&Al[buf][ar * 32 + (lane >> 4) * 8];
      const int bc = wn * 64 + i * 16 + (lane & 15);
      bfr[i] = *(const bf16x8*)&Bl[buf][bc * 32 + (lane >> 4) * 8];
    }
#pragma unroll
    for (int i = 0; i < 4; ++i)
#pragma unroll
      for (int j = 0; j < 4; ++j)
        acc[i][j] = __builtin_amdgcn_mfma_f32_16x16x32_bf16(af[i], bfr[j], acc[i][j], 0, 0, 0);
    __syncthreads();
    buf ^= 1;
  }

#pragma unroll
  for (int i = 0; i < 4; ++i) {
#pragma unroll
    for (int j = 0; j < 4; ++j) {
      const long col = bn + wn * 64 + j * 16 + (lane & 15);
      const float bv = bias[col];
#pragma unroll
      for (int e = 0; e < 4; ++e) {
        const long row = bm + wm * 64 + i * 16 + (lane >> 4) * 4 + e;
        float v = acc[i][j][e] + bv;
        if (MODE == 1) v = fmaxf(v, 0.f);
        if (MODE == 2) {
          const int g = (int)(col >> 10), ub = (int)((col >> 4) & 63), ur = (int)(col & 15);
          C[(row * 64 + ub) * 64 + g * 16 + ur] = f32_to_bf16(v);
        } else {
          C[row * N + col] = f32_to_bf16(v);
        }
      }
    }
  }
}

// ---------------- K3: persistent LSTM recurrence (per-chunk) ----------------
// 128 blocks x 512 thr (8 waves = 2/SIMD), 1 block/CU (~153KB LDS).
// Block (ublk = bid&63, bh = bid>>6) owns 16 units x 32 batches.
// Waves: wb = w>>2 (16-batch half), kq = w&3 (k quarter, 256 each).
// Partials reduced via SoA LDS (lane-stride b32 -> conflict-free).
// h exchange via RELAXED agent-scope 8B atomics (LLC-coherent, no L2 wb/inv);
// hbuf[phase][writer=ublk 64][batch 64 * 4 chunks] (2KB per writer slot),
// the two bh-blocks of a slice fill complementary halves.
// xw PERMUTED: ((t*kB+b)*64+ublk)*64+g*16+u.
__global__ __launch_bounds__(512) void lstm_rec(const unsigned short* __restrict__ xw,
                                                const unsigned short* __restrict__ whh,
                                                const float* __restrict__ h0,
                                                const float* __restrict__ c0,
                                                float* __restrict__ cst,
                                                unsigned long long* __restrict__ hbuf,
                                                unsigned short* __restrict__ hs,
                                                int* __restrict__ flags,
                                                int nsteps, int first, int barbase) {
  __shared__ unsigned short Bl[64 * 1024];     // 128 KB; idx = kc*512 + col*8 + e
  __shared__ unsigned long long hstage[128];   // 1 KB (32 batches x 16 units)
  __shared__ float pacc_f[2][3][4][4][64];     // 24 KB SoA partials
  const int tid = threadIdx.x;
  const int lane = tid & 63;
  const int w = tid >> 6;
  const int wb = w >> 2;   // batch half within block
  const int kq = w & 3;    // k quarter
  const int urow = lane & 15;
  const int bq = lane >> 4;
  const int bid = blockIdx.x;
  const int ublk = bid & 63;
  const int bh = bid >> 6;
  const int u0 = ublk * 16;
  const int lb0 = wb * 16 + bq * 4;   // local batch base (C-frag)
  const int gb0 = bh * 32 + lb0;      // global batch base

  // stage W_hh slice (64 gate-cols x 1024 K) into LDS, k-tiled layout
  for (int idx = tid; idx < 64 * 128; idx += 512) {
    const int col = idx & 63;
    const int kc = idx >> 6;
    const int gcol = (col >> 4) * kH + u0 + (col & 15);
    *(bf16x8*)&Bl[kc * 512 + col * 8] = *(const bf16x8*)&whh[(long)gcol * kH + kc * 8];
  }
  float creg[4];
  if (first) {
    if (tid < 128) {  // publish phase-0 h slice for this (ublk, bh)
      const int lb = tid >> 2, un4 = (tid & 3) * 4, gb = bh * 32 + lb;
      unsigned long long v = 0;
#pragma unroll
      for (int e = 0; e < 4; ++e) {
        const unsigned long long b16 = f32_to_bf16(h0[gb * kH + u0 + un4 + e]);
        v |= b16 << (16 * e);
      }
      coh_store(&hbuf[(size_t)ublk * 256 + bh * 128 + tid], v);
    }
    if (kq == 0)
#pragma unroll
      for (int j = 0; j < 4; ++j) creg[j] = c0[(gb0 + j) * kH + u0 + urow];
  } else {
    if (kq == 0)
#pragma unroll
      for (int j = 0; j < 4; ++j) creg[j] = cst[(gb0 + j) * kH + u0 + urow];
  }

  // entry barrier
  __syncthreads();
  asm volatile("" ::: "memory");
  if (tid == 0)
    __hip_atomic_store(&flags[bid * FLAG_STRIDE], barbase + 1, __ATOMIC_RELAXED,
                       __HIP_MEMORY_SCOPE_AGENT);
  if (tid < RNB)
    while (__hip_atomic_load(&flags[tid * FLAG_STRIDE], __ATOMIC_RELAXED,
                             __HIP_MEMORY_SCOPE_AGENT) < barbase + 1)
      __builtin_amdgcn_s_sleep(1);
  asm volatile("" ::: "memory");
  __syncthreads();

  // x-part of gates for step t (kq0 waves only), prefetched across barrier
  float xv[4][4];
  auto load_xv = [&](int t, float (*dst)[4]) {
#pragma unroll
    for (int j = 0; j < 4; ++j) {
      const unsigned short* xp = xw + ((long)(t * kB + gb0 + j) * 64 + ublk) * 64 + urow;
#pragma unroll
      for (int g = 0; g < 4; ++g) dst[j][g] = bf16_to_f32(xp[g * 16]);
    }
  };
  if (kq == 0) load_xv(0, xv);

  const int abl = wb * 16 + urow;                    // local A-row batch
  const int ach = (bh * 32 + abl) * 4 + (bq & 1) * 2;  // chunk offset in writer slot

  for (int t = 0; t < nsteps; ++t) {
    const unsigned long long* cur = hbuf + (size_t)(t & 1) * (64 * 256);
    unsigned long long* nxt = hbuf + (size_t)((t + 1) & 1) * (64 * 256);

    f32x4 acc[4] = {};
#pragma unroll
    for (int ktl = 0; ktl < 8; ++ktl) {
      const int kt = kq * 8 + ktl;
      // k0 = kt*32 + bq*8 -> writer = kt*2 + (bq>>1)
      const unsigned long long* src = cur + (size_t)(kt * 2 + (bq >> 1)) * 256 + ach;
      union { unsigned long long q[2]; bf16x8 v; } a;
      a.q[0] = coh_load(src);
      a.q[1] = coh_load(src + 1);
      const int kc = kt * 4 + bq;
#pragma unroll
      for (int g = 0; g < 4; ++g) {
        const bf16x8 bb = *(const bf16x8*)&Bl[kc * 512 + (g * 16 + urow) * 8];
        acc[g] = __builtin_amdgcn_mfma_f32_16x16x32_bf16(a.v, bb, acc[g], 0, 0, 0);
      }
    }

    if (kq != 0) {
#pragma unroll
      for (int g = 0; g < 4; ++g)
#pragma unroll
        for (int j = 0; j < 4; ++j) pacc_f[wb][kq - 1][g][j][lane] = acc[g][j];
    }
    __syncthreads();  // partials ready

    if (kq == 0) {
#pragma unroll
      for (int j = 0; j < 4; ++j) {
        float s[4];
#pragma unroll
        for (int g = 0; g < 4; ++g)
          s[g] = acc[g][j] + pacc_f[wb][0][g][j][lane] + pacc_f[wb][1][g][j][lane] +
                 pacc_f[wb][2][g][j][lane] + xv[j][g];
        const float gi = sigmoid_(s[0]);
        const float gf = sigmoid_(s[1]);
        const float gg = tanh_(s[2]);
        const float go = sigmoid_(s[3]);
        creg[j] = gf * creg[j] + gi * gg;
        ((unsigned short*)hstage)[(lb0 + j) * 16 + urow] = f32_to_bf16(go * tanh_(creg[j]));
      }
    }
    __syncthreads();  // hstage complete

    unsigned long long q = 0;
    if (tid < 128) {
      q = hstage[tid];
      coh_store(&nxt[(size_t)ublk * 256 + bh * 128 + tid], q);  // publish h
    }

    __syncthreads();  // per-thread vmcnt drain: publish stores at LLC
    asm volatile("" ::: "memory");
    if (tid == 0)
      __hip_atomic_store(&flags[bid * FLAG_STRIDE], barbase + t + 2, __ATOMIC_RELAXED,
                         __HIP_MEMORY_SCOPE_AGENT);

    // barrier window: hs relu-store + next-step xw prefetch (no pins)
    if (tid < 128) {
      unsigned long long r = 0;
#pragma unroll
      for (int e = 0; e < 4; ++e) {
        unsigned long long s = (q >> (16 * e)) & 0xFFFFull;
        if (s & 0x8000ull) s = 0;
        r |= s << (16 * e);
      }
      const int lb = tid >> 2, un4 = (tid & 3) * 4, gb = bh * 32 + lb;
      *(unsigned long long*)&hs[(long)(t * kB + gb) * kH + u0 + un4] = r;
    }
    float xvn[4][4];
    if (kq == 0 && t + 1 < nsteps) load_xv(t + 1, xvn);

    if (tid < RNB)
      while (__hip_atomic_load(&flags[tid * FLAG_STRIDE], __ATOMIC_RELAXED,
                               __HIP_MEMORY_SCOPE_AGENT) < barbase + t + 2)
        __builtin_amdgcn_s_sleep(1);
    asm volatile("" ::: "memory");
    __syncthreads();

    if (kq == 0 && t + 1 < nsteps) {
#pragma unroll
      for (int j = 0; j < 4; ++j)
#pragma unroll
        for (int g = 0; g < 4; ++g) xv[j][g] = xvn[j][g];
    }
  }

  if (kq == 0)
#pragma unroll
    for (int j = 0; j < 4; ++j) cst[(gb0 + j) * kH + u0 + urow] = creg[j];
}

// ---------------- K5: output head + log_softmax (per-chunk) ----------------
__global__ __launch_bounds__(256) void out_head(const unsigned short* __restrict__ h2,
                                                const unsigned short* __restrict__ ow,
                                                const float* __restrict__ ob,
                                                float* __restrict__ out) {
  __shared__ unsigned short Wl[48 * 1024];  // 96 KB; idx = kc*384 + col*8 + e
  const int tid = threadIdx.x;
  const int lane = tid & 63;
  const int w = tid >> 6;
  for (int idx = tid; idx < 48 * 128; idx += 256) {
    const int col = idx % 48;
    const int kc = idx / 48;
    *(bf16x8*)&Wl[kc * 384 + col * 8] = *(const bf16x8*)&ow[(long)col * kH + kc * 8];
  }
  __syncthreads();
  const long row0 = (long)blockIdx.x * 64 + w * 16;
  f32x4 acc[3] = {};
  const unsigned short* arow = h2 + (row0 + (lane & 15)) * kH + (lane >> 4) * 8;
#pragma unroll 8
  for (int kt = 0; kt < 32; ++kt) {
    const bf16x8 a = *(const bf16x8*)(arow + kt * 32);
    const int kc = kt * 4 + (lane >> 4);
#pragma unroll
    for (int n = 0; n < 3; ++n) {
      const bf16x8 bb = *(const bf16x8*)&Wl[kc * 384 + (n * 16 + (lane & 15)) * 8];
      acc[n] = __builtin_amdgcn_mfma_f32_16x16x32_bf16(a, bb, acc[n], 0, 0, 0);
    }
  }
  const int colb = lane & 15;
#pragma unroll
  for (int j = 0; j < 4; ++j) {
    float v[3];
#pragma unroll
    for (int n = 0; n < 3; ++n) v[n] = acc[n][j] + ob[n * 16 + colb];
    float m = fmaxf(fmaxf(v[0], v[1]), v[2]);
#pragma unroll
    for (int s = 1; s < 16; s <<= 1) m = fmaxf(m, __shfl_xor(m, s, 64));
    float se = __expf(v[0] - m) + __expf(v[1] - m) + __expf(v[2] - m);
#pragma unroll
    for (int s = 1; s < 16; s <<= 1) se += __shfl_xor(se, s, 64);
    const float lse = m + __logf(se);
    const long row = row0 + (lane >> 4) * 4 + j;
#pragma unroll
    for (int n = 0; n < 3; ++n) out[row * 48 + n * 16 + colb] = v[n] - lse;
  }
}

// ---------------- host ----------------
extern "C" void kernel_launch(void* const* d_in, const int* in_sizes, int n_in,
                              void* d_out, int out_size, void* d_ws, size_t ws_size,
                              hipStream_t stream) {
  const float* input_ = (const float*)d_in[0];
  const float* hidden = (const float*)d_in[1];
  const float* cell = (const float*)d_in[2];
  const float* conv_w = (const float*)d_in[3];
  const float* conv_b = (const float*)d_in[4];
  const float* w_ih = (const float*)d_in[5];
  const float* w_hh = (const float*)d_in[6];
  const float* b_ih = (const float*)d_in[7];
  const float* b_hh = (const float*)d_in[8];
  const float* h2h_w = (const float*)d_in[9];
  const float* h2h_b = (const float*)d_in[10];
  const float* out_w = (const float*)d_in[11];
  const float* out_b = (const float*)d_in[12];
  float* out = (float*)d_out;

  // fixed (chunk-independent) footprint
  const size_t FIXED = ((size_t)kG * kLIN + (size_t)kG * kH + (size_t)kH * kH +
                        (size_t)kO * kH) * 2 +
                       (size_t)kG * 4 +
                       2 * (size_t)64 * 256 * 8 +   // hbuf 256KB
                       (size_t)kB * kH * 4 +
                       8192 + 16 * 256;

  // largest chunk (timesteps) whose working set fits ws
  int CHUNK = 2;
  const int cand[] = {512, 256, 128, 64, 32, 16, 8, 4, 2};
  for (int i = 0; i < 9; ++i) {
    const size_t rowsC = (size_t)cand[i] * kB;
    const size_t need = FIXED + rowsC * (kLIN + kG) * 2;
    if (need <= ws_size) { CHUNK = cand[i]; break; }
  }
  const size_t rowsC = (size_t)CHUNK * kB;

  char* ws = (char*)d_ws;
  size_t off = 0;
  auto alloc = [&](size_t bytes) {
    char* p = ws + off;
    off += (bytes + 255) & ~(size_t)255;
    return p;
  };
  unsigned short* regionA = (unsigned short*)alloc(rowsC * kLIN * 2);
  unsigned short* regionB = (unsigned short*)alloc(rowsC * kG * 2);
  unsigned short* wih_b = (unsigned short*)alloc((size_t)kG * kLIN * 2);
  unsigned short* whh_b = (unsigned short*)alloc((size_t)kG * kH * 2);
  unsigned short* h2hw_b = (unsigned short*)alloc((size_t)kH * kH * 2);
  unsigned short* outw_b = (unsigned short*)alloc((size_t)kO * kH * 2);
  float* bias_sum = (float*)alloc((size_t)kG * 4);
  unsigned long long* hbuf = (unsigned long long*)alloc(2 * (size_t)64 * 256 * 8);
  float* cstate = (float*)alloc((size_t)kB * kH * 4);
  int* flags = (int*)alloc(8192);

  unsigned short* feat_c = regionA;
  unsigned short* hs_c = regionA;   // feat dead after gemm<2>
  unsigned short* xw_c = regionB;
  unsigned short* h2_c = regionB;   // xw dead after lstm_rec

  hipMemsetAsync(flags, 0, 8192, stream);
  convert_weights<<<2048, 256, 0, stream>>>(w_ih, w_hh, h2h_w, out_w, b_ih, b_hh, wih_b, whh_b,
                                            h2hw_b, outw_b, bias_sum);

  const int nch = kS / CHUNK;
  for (int ci = 0; ci < nch; ++ci) {
    const long t0 = (long)ci * CHUNK;
    conv_pool<<<(int)(rowsC / 8), 256, 0, stream>>>(input_, conv_w, conv_b, feat_c, t0 * kB);
    gemm_bt_bf16<2><<<dim3((int)(rowsC / 128), kG / 128), 256, 0, stream>>>(
        feat_c, wih_b, bias_sum, xw_c, kG, kLIN);
    lstm_rec<<<RNB, 512, 0, stream>>>(xw_c, whh_b, hidden, cell, cstate, hbuf, hs_c, flags, CHUNK,
                                      ci == 0 ? 1 : 0, ci * (CHUNK + 1));
    gemm_bt_bf16<1><<<dim3((int)(rowsC / 128), kH / 128), 256, 0, stream>>>(
        hs_c, h2hw_b, h2h_b, h2_c, kH, kH);
    out_head<<<(int)(rowsC / 64), 256, 0, stream>>>(h2_c, outw_b, out_b, out + t0 * kB * kO);
  }
}

// Round 9
// 2941.994 us; speedup vs baseline: 3.3208x; 1.1743x over previous
//
#include <hip/hip_runtime.h>
#include <stdint.h>
#include <stddef.h>

// ---------------- problem constants ----------------
#define kS 512
#define kB 64
#define kD 120
#define kOC 16
#define kKSZ 6
#define kPOOL 114
#define kLIN 1824   // 16*114
#define kH 1024
#define kG 4096
#define kO 48
#define kROWS (kS * kB)  // 32768
#define RNB 256          // recurrence blocks: 64 unit-slices x 4 batch-quarters
#define FLAG_STRIDE 16   // ints -> 64B per flag slot

typedef __attribute__((ext_vector_type(8))) short bf16x8;
typedef __attribute__((ext_vector_type(4))) float f32x4;

__device__ __forceinline__ unsigned short f32_to_bf16(float f) {
  unsigned u = __float_as_uint(f);
  u += 0x7FFFu + ((u >> 16) & 1u);
  return (unsigned short)(u >> 16);
}
__device__ __forceinline__ float bf16_to_f32(unsigned short h) {
  return __uint_as_float(((unsigned)h) << 16);
}
__device__ __forceinline__ float sigmoid_(float x) { return 1.f / (1.f + __expf(-x)); }
__device__ __forceinline__ float tanh_(float x) { return 1.f - 2.f / (__expf(2.f * x) + 1.f); }

__device__ __forceinline__ void load_lds_16(const void* g, void* l) {
  __builtin_amdgcn_global_load_lds((__attribute__((address_space(1))) void*)g,
                                   (__attribute__((address_space(3))) void*)l, 16, 0, 0);
}

// relaxed agent-scope 8B ops: sc-coherent loads/stores at LLC, NO wbl2/inv
__device__ __forceinline__ unsigned long long coh_load(const unsigned long long* p) {
  return __hip_atomic_load(p, __ATOMIC_RELAXED, __HIP_MEMORY_SCOPE_AGENT);
}
__device__ __forceinline__ void coh_store(unsigned long long* p, unsigned long long v) {
  __hip_atomic_store(p, v, __ATOMIC_RELAXED, __HIP_MEMORY_SCOPE_AGENT);
}

// ---------------- K0: weight conversion ----------------
__global__ void convert_weights(const float* __restrict__ wih, const float* __restrict__ whh,
                                const float* __restrict__ h2hw, const float* __restrict__ outw,
                                const float* __restrict__ bih, const float* __restrict__ bhh,
                                unsigned short* __restrict__ wihb, unsigned short* __restrict__ whhb,
                                unsigned short* __restrict__ h2hwb, unsigned short* __restrict__ outwb,
                                float* __restrict__ bsum) {
  const size_t N0 = (size_t)kG * kLIN;
  const size_t N1 = (size_t)kG * kH;
  const size_t N2 = (size_t)kH * kH;
  const size_t N3 = (size_t)kO * kH;
  const size_t N4 = kG;
  const size_t TOT = N0 + N1 + N2 + N3 + N4;
  for (size_t i = (size_t)blockIdx.x * blockDim.x + threadIdx.x; i < TOT;
       i += (size_t)gridDim.x * blockDim.x) {
    if (i < N0) wihb[i] = f32_to_bf16(wih[i]);
    else if (i < N0 + N1) whhb[i - N0] = f32_to_bf16(whh[i - N0]);
    else if (i < N0 + N1 + N2) h2hwb[i - N0 - N1] = f32_to_bf16(h2hw[i - N0 - N1]);
    else if (i < N0 + N1 + N2 + N3) outwb[i - N0 - N1 - N2] = f32_to_bf16(outw[i - N0 - N1 - N2]);
    else { size_t j = i - N0 - N1 - N2 - N3; bsum[j] = bih[j] + bhh[j]; }
  }
}

// ---------------- K1: conv1d + relu + maxpool -> feat bf16 (per-chunk) ----------------
__global__ __launch_bounds__(256) void conv_pool(const float* __restrict__ x,
                                                 const float* __restrict__ cw,
                                                 const float* __restrict__ cb,
                                                 unsigned short* __restrict__ feat,
                                                 long row_base) {
  __shared__ float xs[8][kD];
  __shared__ float ws[kOC][kKSZ];
  __shared__ float bs[kOC];
  const int tid = threadIdx.x;
  const long grow0 = row_base + (long)blockIdx.x * 8;
  const long lrow0 = (long)blockIdx.x * 8;
  if (tid < kOC * kKSZ) ws[tid / kKSZ][tid % kKSZ] = cw[tid];
  if (tid < kOC) bs[tid] = cb[tid];
  for (int i = tid; i < 8 * kD; i += 256) xs[i / kD][i % kD] = x[grow0 * kD + i];
  __syncthreads();
  for (int r = 0; r < 8; ++r) {
    for (int idx = tid; idx < kLIN; idx += 256) {
      const int oc = idx / kPOOL, p = idx % kPOOL;
      float c0 = bs[oc], c1 = bs[oc];
#pragma unroll
      for (int k = 0; k < kKSZ; ++k) {
        c0 += xs[r][p + k] * ws[oc][k];
        c1 += xs[r][p + 1 + k] * ws[oc][k];
      }
      float v = fmaxf(fmaxf(c0, c1), 0.f);
      feat[(lrow0 + r) * kLIN + idx] = f32_to_bf16(v);
    }
  }
}

// ---------------- K2/K4: 128x128 bf16 MFMA GEMM ----------------
// MODE 0: C = A@B^T + bias (row-major). MODE 1: relu(...). MODE 2: no relu,
// C written in lstm-permuted layout: col=(g,ublk,ur) -> ((row*64+ublk)*64+g*16+ur)
template <int MODE>
__global__ __launch_bounds__(256) void gemm_bt_bf16(const unsigned short* __restrict__ A,
                                                    const unsigned short* __restrict__ B,
                                                    const float* __restrict__ bias,
                                                    unsigned short* __restrict__ C,
                                                    int N, int K) {
  __shared__ unsigned short Al[2][128 * 32];
  __shared__ unsigned short Bl[2][128 * 32];
  const int tid = threadIdx.x;
  const int lane = tid & 63;
  const int wid = tid >> 6;
  const int wm = wid >> 1, wn = wid & 1;
  const long bm = (long)blockIdx.x * 128;
  const long bn = (long)blockIdx.y * 128;
  const int NT = K / 32;

  f32x4 acc[4][4] = {};

  auto stage = [&](int buf, int kt) {
    const long k0 = (long)kt * 32;
#pragma unroll
    for (int rnd = 0; rnd < 2; ++rnd) {
      const int chunk = rnd * 256 + tid;  // 0..511
      const int r = chunk >> 2, c = chunk & 3;
      load_lds_16(A + (bm + r) * K + k0 + c * 8, &Al[buf][chunk * 8]);
      load_lds_16(B + (bn + r) * K + k0 + c * 8, &Bl[buf][chunk * 8]);
    }
  };

  stage(0, 0);
  __syncthreads();
  int buf = 0;
  for (int kt = 0; kt < NT; ++kt) {
    if (kt + 1 < NT) stage(buf ^ 1, kt + 1);
    bf16x8 af[4], bfr[4];
#pragma unroll
    for (int i = 0; i < 4; ++i) {
      const int ar = wm * 64 + i * 16 + (lane & 15);
      af[i] = *(const bf16x8*)&Al[buf][ar * 32 + (lane >> 4) * 8];
      const int bc = wn * 64 + i * 16 + (lane & 15);
      bfr[i] = *(const bf16x8*)&Bl[buf][bc * 32 + (lane >> 4) * 8];
    }
#pragma unroll
    for (int i = 0; i < 4; ++i)
#pragma unroll
      for (int j = 0; j < 4; ++j)
        acc[i][j] = __builtin_amdgcn_mfma_f32_16x16x32_bf16(af[i], bfr[j], acc[i][j], 0, 0, 0);
    __syncthreads();
    buf ^= 1;
  }

#pragma unroll
  for (int i = 0; i < 4; ++i) {
#pragma unroll
    for (int j = 0; j < 4; ++j) {
      const long col = bn + wn * 64 + j * 16 + (lane & 15);
      const float bv = bias[col];
#pragma unroll
      for (int e = 0; e < 4; ++e) {
        const long row = bm + wm * 64 + i * 16 + (lane >> 4) * 4 + e;
        float v = acc[i][j][e] + bv;
        if (MODE == 1) v = fmaxf(v, 0.f);
        if (MODE == 2) {
          const int g = (int)(col >> 10), ub = (int)((col >> 4) & 63), ur = (int)(col & 15);
          C[(row * 64 + ub) * 64 + g * 16 + ur] = f32_to_bf16(v);
        } else {
          C[row * N + col] = f32_to_bf16(v);
        }
      }
    }
  }
}

// ---------------- K3: persistent LSTM recurrence (per-chunk) ----------------
// 256 blocks x 512 thr, 1 block/CU (160.2KB LDS -> LDS-enforced).
// Block (ublk = bid&63, bqtr = bid>>6) owns 16 units x 16 batches.
// 8 waves split k 8-ways (128 k each); partials SoA-reduced by wave 0.
// h exchange via RELAXED agent-scope 8B atomics (LLC-coherent, no L2 wb/inv);
// hbuf[phase][writer=ublk 64][batch 64 * 4 chunks]; the 4 bqtr-blocks of a
// slice fill complementary quarters. xw PERMUTED: ((t*kB+b)*64+ublk)*64+g*16+u.
__global__ __launch_bounds__(512) void lstm_rec(const unsigned short* __restrict__ xw,
                                                const unsigned short* __restrict__ whh,
                                                const float* __restrict__ h0,
                                                const float* __restrict__ c0,
                                                float* __restrict__ cst,
                                                unsigned long long* __restrict__ hbuf,
                                                unsigned short* __restrict__ hs,
                                                int* __restrict__ flags,
                                                int nsteps, int first, int barbase) {
  __shared__ unsigned short Bl[64 * 1024];     // 128 KB; idx = kc*512 + col*8 + e
  __shared__ unsigned long long hstage[64];    // 512 B (16 batches x 16 units)
  __shared__ float pacc_f[7][4][4][64];        // 28 KB SoA partials (waves 1..7)
  const int tid = threadIdx.x;
  const int lane = tid & 63;
  const int kq = tid >> 6;   // wave = k-eighth
  const int urow = lane & 15;
  const int bq = lane >> 4;
  const int bid = blockIdx.x;
  const int ublk = bid & 63;
  const int bqtr = bid >> 6;
  const int u0 = ublk * 16;
  const int gb0 = bqtr * 16 + bq * 4;  // global batch base of C-frag (wave-0 gates)

  // stage W_hh slice (64 gate-cols x 1024 K) into LDS, k-tiled layout
  for (int idx = tid; idx < 64 * 128; idx += 512) {
    const int col = idx & 63;
    const int kc = idx >> 6;
    const int gcol = (col >> 4) * kH + u0 + (col & 15);
    *(bf16x8*)&Bl[kc * 512 + col * 8] = *(const bf16x8*)&whh[(long)gcol * kH + kc * 8];
  }
  float creg[4];
  if (first) {
    if (tid < 64) {  // publish phase-0 h quarter for this (ublk, bqtr)
      const int lb = tid >> 2, un4 = (tid & 3) * 4, gb = bqtr * 16 + lb;
      unsigned long long v = 0;
#pragma unroll
      for (int e = 0; e < 4; ++e) {
        const unsigned long long b16 = f32_to_bf16(h0[gb * kH + u0 + un4 + e]);
        v |= b16 << (16 * e);
      }
      coh_store(&hbuf[(size_t)ublk * 256 + gb * 4 + (tid & 3)], v);
    }
    if (kq == 0)
#pragma unroll
      for (int j = 0; j < 4; ++j) creg[j] = c0[(gb0 + j) * kH + u0 + urow];
  } else {
    if (kq == 0)
#pragma unroll
      for (int j = 0; j < 4; ++j) creg[j] = cst[(gb0 + j) * kH + u0 + urow];
  }

  // entry barrier
  __syncthreads();
  asm volatile("" ::: "memory");
  if (tid == 0)
    __hip_atomic_store(&flags[bid * FLAG_STRIDE], barbase + 1, __ATOMIC_RELAXED,
                       __HIP_MEMORY_SCOPE_AGENT);
  if (tid < RNB)
    while (__hip_atomic_load(&flags[tid * FLAG_STRIDE], __ATOMIC_RELAXED,
                             __HIP_MEMORY_SCOPE_AGENT) < barbase + 1)
      __builtin_amdgcn_s_sleep(1);
  asm volatile("" ::: "memory");
  __syncthreads();

  // x-part of gates for step t (wave-0 only), prefetched across barrier
  float xv[4][4];
  auto load_xv = [&](int t, float (*dst)[4]) {
#pragma unroll
    for (int j = 0; j < 4; ++j) {
      const unsigned short* xp = xw + ((long)(t * kB + gb0 + j) * 64 + ublk) * 64 + urow;
#pragma unroll
      for (int g = 0; g < 4; ++g) dst[j][g] = bf16_to_f32(xp[g * 16]);
    }
  };
  if (kq == 0) load_xv(0, xv);

  // A-frag chunk offset in writer slot: batch = bqtr*16 + (lane&15)
  const int ach = (bqtr * 16 + urow) * 4 + (bq & 1) * 2;

  for (int t = 0; t < nsteps; ++t) {
    const unsigned long long* cur = hbuf + (size_t)(t & 1) * (64 * 256);
    unsigned long long* nxt = hbuf + (size_t)((t + 1) & 1) * (64 * 256);

    f32x4 acc[4] = {};
#pragma unroll
    for (int ktl = 0; ktl < 4; ++ktl) {
      const int kt = kq * 4 + ktl;
      // k0 = kt*32 + bq*8 -> writer = kt*2 + (bq>>1)
      const unsigned long long* src = cur + (size_t)(kt * 2 + (bq >> 1)) * 256 + ach;
      union { unsigned long long q[2]; bf16x8 v; } a;
      a.q[0] = coh_load(src);
      a.q[1] = coh_load(src + 1);
      const int kc = kt * 4 + bq;
#pragma unroll
      for (int g = 0; g < 4; ++g) {
        const bf16x8 bb = *(const bf16x8*)&Bl[kc * 512 + (g * 16 + urow) * 8];
        acc[g] = __builtin_amdgcn_mfma_f32_16x16x32_bf16(a.v, bb, acc[g], 0, 0, 0);
      }
    }

    if (kq != 0) {
#pragma unroll
      for (int g = 0; g < 4; ++g)
#pragma unroll
        for (int j = 0; j < 4; ++j) pacc_f[kq - 1][g][j][lane] = acc[g][j];
    }
    __syncthreads();  // partials ready

    if (kq == 0) {
#pragma unroll
      for (int j = 0; j < 4; ++j) {
        float s[4];
#pragma unroll
        for (int g = 0; g < 4; ++g) {
          float sum = acc[g][j] + xv[j][g];
#pragma unroll
          for (int p = 0; p < 7; ++p) sum += pacc_f[p][g][j][lane];
          s[g] = sum;
        }
        const float gi = sigmoid_(s[0]);
        const float gf = sigmoid_(s[1]);
        const float gg = tanh_(s[2]);
        const float go = sigmoid_(s[3]);
        creg[j] = gf * creg[j] + gi * gg;
        ((unsigned short*)hstage)[(bq * 4 + j) * 16 + urow] = f32_to_bf16(go * tanh_(creg[j]));
      }
    }
    __syncthreads();  // hstage complete

    unsigned long long q = 0;
    if (tid < 64) {
      q = hstage[tid];
      coh_store(&nxt[(size_t)ublk * 256 + (bqtr * 16 + (tid >> 2)) * 4 + (tid & 3)], q);
    }

    __syncthreads();  // per-wave vmcnt drain: publish stores at LLC
    asm volatile("" ::: "memory");
    if (tid == 0)
      __hip_atomic_store(&flags[bid * FLAG_STRIDE], barbase + t + 2, __ATOMIC_RELAXED,
                         __HIP_MEMORY_SCOPE_AGENT);

    // barrier window: hs relu-store + next-step xw prefetch (no pins)
    if (tid < 64) {
      unsigned long long r = 0;
#pragma unroll
      for (int e = 0; e < 4; ++e) {
        unsigned long long s = (q >> (16 * e)) & 0xFFFFull;
        if (s & 0x8000ull) s = 0;
        r |= s << (16 * e);
      }
      const int lb = tid >> 2, un4 = (tid & 3) * 4, gb = bqtr * 16 + lb;
      *(unsigned long long*)&hs[(long)(t * kB + gb) * kH + u0 + un4] = r;
    }
    float xvn[4][4];
    if (kq == 0 && t + 1 < nsteps) load_xv(t + 1, xvn);

    if (tid < RNB)
      while (__hip_atomic_load(&flags[tid * FLAG_STRIDE], __ATOMIC_RELAXED,
                               __HIP_MEMORY_SCOPE_AGENT) < barbase + t + 2)
        __builtin_amdgcn_s_sleep(1);
    asm volatile("" ::: "memory");
    __syncthreads();

    if (kq == 0 && t + 1 < nsteps) {
#pragma unroll
      for (int j = 0; j < 4; ++j)
#pragma unroll
        for (int g = 0; g < 4; ++g) xv[j][g] = xvn[j][g];
    }
  }

  if (kq == 0)
#pragma unroll
    for (int j = 0; j < 4; ++j) cst[(gb0 + j) * kH + u0 + urow] = creg[j];
}

// ---------------- K5: output head + log_softmax (per-chunk) ----------------
__global__ __launch_bounds__(256) void out_head(const unsigned short* __restrict__ h2,
                                                const unsigned short* __restrict__ ow,
                                                const float* __restrict__ ob,
                                                float* __restrict__ out) {
  __shared__ unsigned short Wl[48 * 1024];  // 96 KB; idx = kc*384 + col*8 + e
  const int tid = threadIdx.x;
  const int lane = tid & 63;
  const int w = tid >> 6;
  for (int idx = tid; idx < 48 * 128; idx += 256) {
    const int col = idx % 48;
    const int kc = idx / 48;
    *(bf16x8*)&Wl[kc * 384 + col * 8] = *(const bf16x8*)&ow[(long)col * kH + kc * 8];
  }
  __syncthreads();
  const long row0 = (long)blockIdx.x * 64 + w * 16;
  f32x4 acc[3] = {};
  const unsigned short* arow = h2 + (row0 + (lane & 15)) * kH + (lane >> 4) * 8;
#pragma unroll 8
  for (int kt = 0; kt < 32; ++kt) {
    const bf16x8 a = *(const bf16x8*)(arow + kt * 32);
    const int kc = kt * 4 + (lane >> 4);
#pragma unroll
    for (int n = 0; n < 3; ++n) {
      const bf16x8 bb = *(const bf16x8*)&Wl[kc * 384 + (n * 16 + (lane & 15)) * 8];
      acc[n] = __builtin_amdgcn_mfma_f32_16x16x32_bf16(a, bb, acc[n], 0, 0, 0);
    }
  }
  const int colb = lane & 15;
#pragma unroll
  for (int j = 0; j < 4; ++j) {
    float v[3];
#pragma unroll
    for (int n = 0; n < 3; ++n) v[n] = acc[n][j] + ob[n * 16 + colb];
    float m = fmaxf(fmaxf(v[0], v[1]), v[2]);
#pragma unroll
    for (int s = 1; s < 16; s <<= 1) m = fmaxf(m, __shfl_xor(m, s, 64));
    float se = __expf(v[0] - m) + __expf(v[1] - m) + __expf(v[2] - m);
#pragma unroll
    for (int s = 1; s < 16; s <<= 1) se += __shfl_xor(se, s, 64);
    const float lse = m + __logf(se);
    const long row = row0 + (lane >> 4) * 4 + j;
#pragma unroll
    for (int n = 0; n < 3; ++n) out[row * 48 + n * 16 + colb] = v[n] - lse;
  }
}

// ---------------- host ----------------
extern "C" void kernel_launch(void* const* d_in, const int* in_sizes, int n_in,
                              void* d_out, int out_size, void* d_ws, size_t ws_size,
                              hipStream_t stream) {
  const float* input_ = (const float*)d_in[0];
  const float* hidden = (const float*)d_in[1];
  const float* cell = (const float*)d_in[2];
  const float* conv_w = (const float*)d_in[3];
  const float* conv_b = (const float*)d_in[4];
  const float* w_ih = (const float*)d_in[5];
  const float* w_hh = (const float*)d_in[6];
  const float* b_ih = (const float*)d_in[7];
  const float* b_hh = (const float*)d_in[8];
  const float* h2h_w = (const float*)d_in[9];
  const float* h2h_b = (const float*)d_in[10];
  const float* out_w = (const float*)d_in[11];
  const float* out_b = (const float*)d_in[12];
  float* out = (float*)d_out;

  // fixed (chunk-independent) footprint
  const size_t FIXED = ((size_t)kG * kLIN + (size_t)kG * kH + (size_t)kH * kH +
                        (size_t)kO * kH) * 2 +
                       (size_t)kG * 4 +
                       2 * (size_t)64 * 256 * 8 +   // hbuf 256KB
                       (size_t)kB * kH * 4 +
                       16384 + 16 * 256;

  // largest chunk (timesteps) whose working set fits ws
  int CHUNK = 2;
  const int cand[] = {512, 256, 128, 64, 32, 16, 8, 4, 2};
  for (int i = 0; i < 9; ++i) {
    const size_t rowsC = (size_t)cand[i] * kB;
    const size_t need = FIXED + rowsC * (kLIN + kG) * 2;
    if (need <= ws_size) { CHUNK = cand[i]; break; }
  }
  const size_t rowsC = (size_t)CHUNK * kB;

  char* ws = (char*)d_ws;
  size_t off = 0;
  auto alloc = [&](size_t bytes) {
    char* p = ws + off;
    off += (bytes + 255) & ~(size_t)255;
    return p;
  };
  unsigned short* regionA = (unsigned short*)alloc(rowsC * kLIN * 2);
  unsigned short* regionB = (unsigned short*)alloc(rowsC * kG * 2);
  unsigned short* wih_b = (unsigned short*)alloc((size_t)kG * kLIN * 2);
  unsigned short* whh_b = (unsigned short*)alloc((size_t)kG * kH * 2);
  unsigned short* h2hw_b = (unsigned short*)alloc((size_t)kH * kH * 2);
  unsigned short* outw_b = (unsigned short*)alloc((size_t)kO * kH * 2);
  float* bias_sum = (float*)alloc((size_t)kG * 4);
  unsigned long long* hbuf = (unsigned long long*)alloc(2 * (size_t)64 * 256 * 8);
  float* cstate = (float*)alloc((size_t)kB * kH * 4);
  int* flags = (int*)alloc(16384);

  unsigned short* feat_c = regionA;
  unsigned short* hs_c = regionA;   // feat dead after gemm<2>
  unsigned short* xw_c = regionB;
  unsigned short* h2_c = regionB;   // xw dead after lstm_rec

  hipMemsetAsync(flags, 0, 16384, stream);
  convert_weights<<<2048, 256, 0, stream>>>(w_ih, w_hh, h2h_w, out_w, b_ih, b_hh, wih_b, whh_b,
                                            h2hw_b, outw_b, bias_sum);

  const int nch = kS / CHUNK;
  for (int ci = 0; ci < nch; ++ci) {
    const long t0 = (long)ci * CHUNK;
    conv_pool<<<(int)(rowsC / 8), 256, 0, stream>>>(input_, conv_w, conv_b, feat_c, t0 * kB);
    gemm_bt_bf16<2><<<dim3((int)(rowsC / 128), kG / 128), 256, 0, stream>>>(
        feat_c, wih_b, bias_sum, xw_c, kG, kLIN);
    lstm_rec<<<RNB, 512, 0, stream>>>(xw_c, whh_b, hidden, cell, cstate, hbuf, hs_c, flags, CHUNK,
                                      ci == 0 ? 1 : 0, ci * (CHUNK + 1));
    gemm_bt_bf16<1><<<dim3((int)(rowsC / 128), kH / 128), 256, 0, stream>>>(
        hs_c, h2hw_b, h2h_b, h2_c, kH, kH);
    out_head<<<(int)(rowsC / 64), 256, 0, stream>>>(h2_c, outw_b, out_b, out + t0 * kB * kO);
  }
}

// Round 10
// 2872.727 us; speedup vs baseline: 3.4009x; 1.0241x over previous
//
#include <hip/hip_runtime.h>
#include <stdint.h>
#include <stddef.h>

// ---------------- problem constants ----------------
#define kS 512
#define kB 64
#define kD 120
#define kOC 16
#define kKSZ 6
#define kPOOL 114
#define kLIN 1824   // 16*114
#define kH 1024
#define kG 4096
#define kO 48
#define kROWS (kS * kB)  // 32768
#define RNB 256          // recurrence blocks: 64 unit-slices x 4 batch-quarters
#define FLAG_STRIDE 16   // ints -> 64B per flag slot

typedef __attribute__((ext_vector_type(8))) short bf16x8;
typedef __attribute__((ext_vector_type(4))) float f32x4;

__device__ __forceinline__ unsigned short f32_to_bf16(float f) {
  unsigned u = __float_as_uint(f);
  u += 0x7FFFu + ((u >> 16) & 1u);
  return (unsigned short)(u >> 16);
}
__device__ __forceinline__ float bf16_to_f32(unsigned short h) {
  return __uint_as_float(((unsigned)h) << 16);
}
__device__ __forceinline__ float sigmoid_(float x) { return 1.f / (1.f + __expf(-x)); }
__device__ __forceinline__ float tanh_(float x) { return 1.f - 2.f / (__expf(2.f * x) + 1.f); }

__device__ __forceinline__ void load_lds_16(const void* g, void* l) {
  __builtin_amdgcn_global_load_lds((__attribute__((address_space(1))) void*)g,
                                   (__attribute__((address_space(3))) void*)l, 16, 0, 0);
}

// relaxed agent-scope 8B ops: sc-coherent loads/stores at LLC, NO wbl2/inv
__device__ __forceinline__ unsigned long long coh_load(const unsigned long long* p) {
  return __hip_atomic_load(p, __ATOMIC_RELAXED, __HIP_MEMORY_SCOPE_AGENT);
}
__device__ __forceinline__ void coh_store(unsigned long long* p, unsigned long long v) {
  __hip_atomic_store(p, v, __ATOMIC_RELAXED, __HIP_MEMORY_SCOPE_AGENT);
}

// ---------------- K0: weight conversion ----------------
__global__ void convert_weights(const float* __restrict__ wih, const float* __restrict__ whh,
                                const float* __restrict__ h2hw, const float* __restrict__ outw,
                                const float* __restrict__ bih, const float* __restrict__ bhh,
                                unsigned short* __restrict__ wihb, unsigned short* __restrict__ whhb,
                                unsigned short* __restrict__ h2hwb, unsigned short* __restrict__ outwb,
                                float* __restrict__ bsum) {
  const size_t N0 = (size_t)kG * kLIN;
  const size_t N1 = (size_t)kG * kH;
  const size_t N2 = (size_t)kH * kH;
  const size_t N3 = (size_t)kO * kH;
  const size_t N4 = kG;
  const size_t TOT = N0 + N1 + N2 + N3 + N4;
  for (size_t i = (size_t)blockIdx.x * blockDim.x + threadIdx.x; i < TOT;
       i += (size_t)gridDim.x * blockDim.x) {
    if (i < N0) wihb[i] = f32_to_bf16(wih[i]);
    else if (i < N0 + N1) whhb[i - N0] = f32_to_bf16(whh[i - N0]);
    else if (i < N0 + N1 + N2) h2hwb[i - N0 - N1] = f32_to_bf16(h2hw[i - N0 - N1]);
    else if (i < N0 + N1 + N2 + N3) outwb[i - N0 - N1 - N2] = f32_to_bf16(outw[i - N0 - N1 - N2]);
    else { size_t j = i - N0 - N1 - N2 - N3; bsum[j] = bih[j] + bhh[j]; }
  }
}

// ---------------- K1: conv1d + relu + maxpool -> feat bf16 (per-chunk) ----------------
__global__ __launch_bounds__(256) void conv_pool(const float* __restrict__ x,
                                                 const float* __restrict__ cw,
                                                 const float* __restrict__ cb,
                                                 unsigned short* __restrict__ feat,
                                                 long row_base) {
  __shared__ float xs[8][kD];
  __shared__ float ws[kOC][kKSZ];
  __shared__ float bs[kOC];
  const int tid = threadIdx.x;
  const long grow0 = row_base + (long)blockIdx.x * 8;
  const long lrow0 = (long)blockIdx.x * 8;
  if (tid < kOC * kKSZ) ws[tid / kKSZ][tid % kKSZ] = cw[tid];
  if (tid < kOC) bs[tid] = cb[tid];
  for (int i = tid; i < 8 * kD; i += 256) xs[i / kD][i % kD] = x[grow0 * kD + i];
  __syncthreads();
  for (int r = 0; r < 8; ++r) {
    for (int idx = tid; idx < kLIN; idx += 256) {
      const int oc = idx / kPOOL, p = idx % kPOOL;
      float c0 = bs[oc], c1 = bs[oc];
#pragma unroll
      for (int k = 0; k < kKSZ; ++k) {
        c0 += xs[r][p + k] * ws[oc][k];
        c1 += xs[r][p + 1 + k] * ws[oc][k];
      }
      float v = fmaxf(fmaxf(c0, c1), 0.f);
      feat[(lrow0 + r) * kLIN + idx] = f32_to_bf16(v);
    }
  }
}

// ---------------- K2/K4: 128x128 bf16 MFMA GEMM ----------------
// MODE 0: C = A@B^T + bias (row-major). MODE 1: relu(...). MODE 2: no relu,
// C written in lstm-permuted layout: col=(g,ublk,ur) -> ((row*64+ublk)*64+g*16+ur)
template <int MODE>
__global__ __launch_bounds__(256) void gemm_bt_bf16(const unsigned short* __restrict__ A,
                                                    const unsigned short* __restrict__ B,
                                                    const float* __restrict__ bias,
                                                    unsigned short* __restrict__ C,
                                                    int N, int K) {
  __shared__ unsigned short Al[2][128 * 32];
  __shared__ unsigned short Bl[2][128 * 32];
  const int tid = threadIdx.x;
  const int lane = tid & 63;
  const int wid = tid >> 6;
  const int wm = wid >> 1, wn = wid & 1;
  const long bm = (long)blockIdx.x * 128;
  const long bn = (long)blockIdx.y * 128;
  const int NT = K / 32;

  f32x4 acc[4][4] = {};

  auto stage = [&](int buf, int kt) {
    const long k0 = (long)kt * 32;
#pragma unroll
    for (int rnd = 0; rnd < 2; ++rnd) {
      const int chunk = rnd * 256 + tid;  // 0..511
      const int r = chunk >> 2, c = chunk & 3;
      load_lds_16(A + (bm + r) * K + k0 + c * 8, &Al[buf][chunk * 8]);
      load_lds_16(B + (bn + r) * K + k0 + c * 8, &Bl[buf][chunk * 8]);
    }
  };

  stage(0, 0);
  __syncthreads();
  int buf = 0;
  for (int kt = 0; kt < NT; ++kt) {
    if (kt + 1 < NT) stage(buf ^ 1, kt + 1);
    bf16x8 af[4], bfr[4];
#pragma unroll
    for (int i = 0; i < 4; ++i) {
      const int ar = wm * 64 + i * 16 + (lane & 15);
      af[i] = *(const bf16x8*)&Al[buf][ar * 32 + (lane >> 4) * 8];
      const int bc = wn * 64 + i * 16 + (lane & 15);
      bfr[i] = *(const bf16x8*)&Bl[buf][bc * 32 + (lane >> 4) * 8];
    }
#pragma unroll
    for (int i = 0; i < 4; ++i)
#pragma unroll
      for (int j = 0; j < 4; ++j)
        acc[i][j] = __builtin_amdgcn_mfma_f32_16x16x32_bf16(af[i], bfr[j], acc[i][j], 0, 0, 0);
    __syncthreads();
    buf ^= 1;
  }

#pragma unroll
  for (int i = 0; i < 4; ++i) {
#pragma unroll
    for (int j = 0; j < 4; ++j) {
      const long col = bn + wn * 64 + j * 16 + (lane & 15);
      const float bv = bias[col];
#pragma unroll
      for (int e = 0; e < 4; ++e) {
        const long row = bm + wm * 64 + i * 16 + (lane >> 4) * 4 + e;
        float v = acc[i][j][e] + bv;
        if (MODE == 1) v = fmaxf(v, 0.f);
        if (MODE == 2) {
          const int g = (int)(col >> 10), ub = (int)((col >> 4) & 63), ur = (int)(col & 15);
          C[(row * 64 + ub) * 64 + g * 16 + ur] = f32_to_bf16(v);
        } else {
          C[row * N + col] = f32_to_bf16(v);
        }
      }
    }
  }
}

// ---------------- K3: persistent LSTM recurrence (per-chunk) ----------------
// 256 blocks x 512 thr, 1 block/CU. Block (ublk=bid&63, bqtr=bid>>6) owns
// 16 units x 16 batches; 8 waves split k 8-ways (wave kq reads writer ublks
// [kq*8, kq*8+8) of its own batch quarter ONLY).
// DATAFLOW SYNC: no grid barrier. Each wave polls just its 8 producer blocks'
// flags (lanes 0-7, one flag each) then proceeds. Safe with double-buffered
// hbuf: a block publishes h(t+1) only after all its waves saw all producers
// publish h(t) => every same-quarter block finished reading h(t-1).
// Wave 0 alone does reduce/gates/publish/signal/hs; waves 1-7 run ahead.
__global__ __launch_bounds__(512) void lstm_rec(const unsigned short* __restrict__ xw,
                                                const unsigned short* __restrict__ whh,
                                                const float* __restrict__ h0,
                                                const float* __restrict__ c0,
                                                float* __restrict__ cst,
                                                unsigned long long* __restrict__ hbuf,
                                                unsigned short* __restrict__ hs,
                                                int* __restrict__ flags,
                                                int nsteps, int first, int barbase) {
  __shared__ unsigned short Bl[64 * 1024];     // 128 KB; idx = kc*512 + col*8 + e
  __shared__ unsigned long long hstage[64];    // 512 B (16 batches x 16 units)
  __shared__ float pacc_f[7][4][4][64];        // 28 KB SoA partials (waves 1..7)
  const int tid = threadIdx.x;
  const int lane = tid & 63;
  const int kq = tid >> 6;   // wave = k-eighth
  const int urow = lane & 15;
  const int bq = lane >> 4;
  const int bid = blockIdx.x;
  const int ublk = bid & 63;
  const int bqtr = bid >> 6;
  const int u0 = ublk * 16;
  const int gb0 = bqtr * 16 + bq * 4;  // global batch base of C-frag (wave-0 gates)

  // this wave's producer block (lanes 0..7 poll one each)
  const int prodbid = bqtr * 64 + kq * 8 + (lane & 7);

  // stage W_hh slice (64 gate-cols x 1024 K) into LDS, k-tiled layout
  for (int idx = tid; idx < 64 * 128; idx += 512) {
    const int col = idx & 63;
    const int kc = idx >> 6;
    const int gcol = (col >> 4) * kH + u0 + (col & 15);
    *(bf16x8*)&Bl[kc * 512 + col * 8] = *(const bf16x8*)&whh[(long)gcol * kH + kc * 8];
  }
  float creg[4];
  if (first) {
    if (tid < 64) {  // publish phase-0 h quarter for this (ublk, bqtr)
      const int lb = tid >> 2, un4 = (tid & 3) * 4, gb = bqtr * 16 + lb;
      unsigned long long v = 0;
#pragma unroll
      for (int e = 0; e < 4; ++e) {
        const unsigned long long b16 = f32_to_bf16(h0[gb * kH + u0 + un4 + e]);
        v |= b16 << (16 * e);
      }
      coh_store(&hbuf[(size_t)ublk * 256 + gb * 4 + (tid & 3)], v);
    }
    if (kq == 0)
#pragma unroll
      for (int j = 0; j < 4; ++j) creg[j] = c0[(gb0 + j) * kH + u0 + urow];
  } else {
    if (kq == 0)
#pragma unroll
      for (int j = 0; j < 4; ++j) creg[j] = cst[(gb0 + j) * kH + u0 + urow];
  }

  // entry barrier (once per chunk): full poll, covers h0 publish visibility
  __syncthreads();
  asm volatile("" ::: "memory");
  if (tid == 0)
    __hip_atomic_store(&flags[bid * FLAG_STRIDE], barbase + 1, __ATOMIC_RELAXED,
                       __HIP_MEMORY_SCOPE_AGENT);
  if (tid < RNB)
    while (__hip_atomic_load(&flags[tid * FLAG_STRIDE], __ATOMIC_RELAXED,
                             __HIP_MEMORY_SCOPE_AGENT) < barbase + 1)
      __builtin_amdgcn_s_sleep(1);
  asm volatile("" ::: "memory");
  __syncthreads();

  // x-part of gates for step t (wave-0 only)
  float xv[4][4];
  auto load_xv = [&](int t, float (*dst)[4]) {
#pragma unroll
    for (int j = 0; j < 4; ++j) {
      const unsigned short* xp = xw + ((long)(t * kB + gb0 + j) * 64 + ublk) * 64 + urow;
#pragma unroll
      for (int g = 0; g < 4; ++g) dst[j][g] = bf16_to_f32(xp[g * 16]);
    }
  };
  if (kq == 0) load_xv(0, xv);

  // A-frag chunk offset in writer slot: batch = bqtr*16 + (lane&15)
  const int ach = (bqtr * 16 + urow) * 4 + (bq & 1) * 2;

  for (int t = 0; t < nsteps; ++t) {
    const unsigned long long* cur = hbuf + (size_t)(t & 1) * (64 * 256);
    unsigned long long* nxt = hbuf + (size_t)((t + 1) & 1) * (64 * 256);

    // WAVE-LOCAL dataflow wait: my 8 producers must have published h(t)
    if ((lane & 63) < 8) {
      while (__hip_atomic_load(&flags[prodbid * FLAG_STRIDE], __ATOMIC_RELAXED,
                               __HIP_MEMORY_SCOPE_AGENT) < barbase + t + 1)
        __builtin_amdgcn_s_sleep(1);
    }
    asm volatile("" ::: "memory");

    f32x4 acc[4] = {};
#pragma unroll
    for (int ktl = 0; ktl < 4; ++ktl) {
      const int kt = kq * 4 + ktl;
      // k0 = kt*32 + bq*8 -> writer = kt*2 + (bq>>1)
      const unsigned long long* src = cur + (size_t)(kt * 2 + (bq >> 1)) * 256 + ach;
      union { unsigned long long q[2]; bf16x8 v; } a;
      a.q[0] = coh_load(src);
      a.q[1] = coh_load(src + 1);
      const int kc = kt * 4 + bq;
#pragma unroll
      for (int g = 0; g < 4; ++g) {
        const bf16x8 bb = *(const bf16x8*)&Bl[kc * 512 + (g * 16 + urow) * 8];
        acc[g] = __builtin_amdgcn_mfma_f32_16x16x32_bf16(a.v, bb, acc[g], 0, 0, 0);
      }
    }

    if (kq != 0) {
#pragma unroll
      for (int g = 0; g < 4; ++g)
#pragma unroll
        for (int j = 0; j < 4; ++j) pacc_f[kq - 1][g][j][lane] = acc[g][j];
    }
    __syncthreads();  // partials ready

    if (kq == 0) {
#pragma unroll
      for (int j = 0; j < 4; ++j) {
        float s[4];
#pragma unroll
        for (int g = 0; g < 4; ++g) {
          float sum = acc[g][j] + xv[j][g];
#pragma unroll
          for (int p = 0; p < 7; ++p) sum += pacc_f[p][g][j][lane];
          s[g] = sum;
        }
        const float gi = sigmoid_(s[0]);
        const float gf = sigmoid_(s[1]);
        const float gg = tanh_(s[2]);
        const float go = sigmoid_(s[3]);
        creg[j] = gf * creg[j] + gi * gg;
        ((unsigned short*)hstage)[(bq * 4 + j) * 16 + urow] = f32_to_bf16(go * tanh_(creg[j]));
      }
    }
    __syncthreads();  // pacc consumed + hstage complete; waves 1-7 run ahead

    if (kq == 0) {
      const unsigned long long q = hstage[lane];
      coh_store(&nxt[(size_t)ublk * 256 + (bqtr * 16 + (lane >> 2)) * 4 + (lane & 3)], q);
      asm volatile("s_waitcnt vmcnt(0)" ::: "memory");  // publish at LLC
      if (lane == 0)
        __hip_atomic_store(&flags[bid * FLAG_STRIDE], barbase + t + 2, __ATOMIC_RELAXED,
                           __HIP_MEMORY_SCOPE_AGENT);
      // off critical path: hs relu-store + next-step xw prefetch
      unsigned long long r = 0;
#pragma unroll
      for (int e = 0; e < 4; ++e) {
        unsigned long long s = (q >> (16 * e)) & 0xFFFFull;
        if (s & 0x8000ull) s = 0;
        r |= s << (16 * e);
      }
      const int lb = lane >> 2, un4 = (lane & 3) * 4, gb = bqtr * 16 + lb;
      *(unsigned long long*)&hs[(long)(t * kB + gb) * kH + u0 + un4] = r;
      if (t + 1 < nsteps) load_xv(t + 1, xv);
    }
  }

  if (kq == 0)
#pragma unroll
    for (int j = 0; j < 4; ++j) cst[(gb0 + j) * kH + u0 + urow] = creg[j];
}

// ---------------- K5: output head + log_softmax (per-chunk) ----------------
__global__ __launch_bounds__(256) void out_head(const unsigned short* __restrict__ h2,
                                                const unsigned short* __restrict__ ow,
                                                const float* __restrict__ ob,
                                                float* __restrict__ out) {
  __shared__ unsigned short Wl[48 * 1024];  // 96 KB; idx = kc*384 + col*8 + e
  const int tid = threadIdx.x;
  const int lane = tid & 63;
  const int w = tid >> 6;
  for (int idx = tid; idx < 48 * 128; idx += 256) {
    const int col = idx % 48;
    const int kc = idx / 48;
    *(bf16x8*)&Wl[kc * 384 + col * 8] = *(const bf16x8*)&ow[(long)col * kH + kc * 8];
  }
  __syncthreads();
  const long row0 = (long)blockIdx.x * 64 + w * 16;
  f32x4 acc[3] = {};
  const unsigned short* arow = h2 + (row0 + (lane & 15)) * kH + (lane >> 4) * 8;
#pragma unroll 8
  for (int kt = 0; kt < 32; ++kt) {
    const bf16x8 a = *(const bf16x8*)(arow + kt * 32);
    const int kc = kt * 4 + (lane >> 4);
#pragma unroll
    for (int n = 0; n < 3; ++n) {
      const bf16x8 bb = *(const bf16x8*)&Wl[kc * 384 + (n * 16 + (lane & 15)) * 8];
      acc[n] = __builtin_amdgcn_mfma_f32_16x16x32_bf16(a, bb, acc[n], 0, 0, 0);
    }
  }
  const int colb = lane & 15;
#pragma unroll
  for (int j = 0; j < 4; ++j) {
    float v[3];
#pragma unroll
    for (int n = 0; n < 3; ++n) v[n] = acc[n][j] + ob[n * 16 + colb];
    float m = fmaxf(fmaxf(v[0], v[1]), v[2]);
#pragma unroll
    for (int s = 1; s < 16; s <<= 1) m = fmaxf(m, __shfl_xor(m, s, 64));
    float se = __expf(v[0] - m) + __expf(v[1] - m) + __expf(v[2] - m);
#pragma unroll
    for (int s = 1; s < 16; s <<= 1) se += __shfl_xor(se, s, 64);
    const float lse = m + __logf(se);
    const long row = row0 + (lane >> 4) * 4 + j;
#pragma unroll
    for (int n = 0; n < 3; ++n) out[row * 48 + n * 16 + colb] = v[n] - lse;
  }
}

// ---------------- host ----------------
extern "C" void kernel_launch(void* const* d_in, const int* in_sizes, int n_in,
                              void* d_out, int out_size, void* d_ws, size_t ws_size,
                              hipStream_t stream) {
  const float* input_ = (const float*)d_in[0];
  const float* hidden = (const float*)d_in[1];
  const float* cell = (const float*)d_in[2];
  const float* conv_w = (const float*)d_in[3];
  const float* conv_b = (const float*)d_in[4];
  const float* w_ih = (const float*)d_in[5];
  const float* w_hh = (const float*)d_in[6];
  const float* b_ih = (const float*)d_in[7];
  const float* b_hh = (const float*)d_in[8];
  const float* h2h_w = (const float*)d_in[9];
  const float* h2h_b = (const float*)d_in[10];
  const float* out_w = (const float*)d_in[11];
  const float* out_b = (const float*)d_in[12];
  float* out = (float*)d_out;

  // fixed (chunk-independent) footprint
  const size_t FIXED = ((size_t)kG * kLIN + (size_t)kG * kH + (size_t)kH * kH +
                        (size_t)kO * kH) * 2 +
                       (size_t)kG * 4 +
                       2 * (size_t)64 * 256 * 8 +   // hbuf 256KB
                       (size_t)kB * kH * 4 +
                       16384 + 16 * 256;

  // largest chunk (timesteps) whose working set fits ws
  int CHUNK = 2;
  const int cand[] = {512, 256, 128, 64, 32, 16, 8, 4, 2};
  for (int i = 0; i < 9; ++i) {
    const size_t rowsC = (size_t)cand[i] * kB;
    const size_t need = FIXED + rowsC * (kLIN + kG) * 2;
    if (need <= ws_size) { CHUNK = cand[i]; break; }
  }
  const size_t rowsC = (size_t)CHUNK * kB;

  char* ws = (char*)d_ws;
  size_t off = 0;
  auto alloc = [&](size_t bytes) {
    char* p = ws + off;
    off += (bytes + 255) & ~(size_t)255;
    return p;
  };
  unsigned short* regionA = (unsigned short*)alloc(rowsC * kLIN * 2);
  unsigned short* regionB = (unsigned short*)alloc(rowsC * kG * 2);
  unsigned short* wih_b = (unsigned short*)alloc((size_t)kG * kLIN * 2);
  unsigned short* whh_b = (unsigned short*)alloc((size_t)kG * kH * 2);
  unsigned short* h2hw_b = (unsigned short*)alloc((size_t)kH * kH * 2);
  unsigned short* outw_b = (unsigned short*)alloc((size_t)kO * kH * 2);
  float* bias_sum = (float*)alloc((size_t)kG * 4);
  unsigned long long* hbuf = (unsigned long long*)alloc(2 * (size_t)64 * 256 * 8);
  float* cstate = (float*)alloc((size_t)kB * kH * 4);
  int* flags = (int*)alloc(16384);

  unsigned short* feat_c = regionA;
  unsigned short* hs_c = regionA;   // feat dead after gemm<2>
  unsigned short* xw_c = regionB;
  unsigned short* h2_c = regionB;   // xw dead after lstm_rec

  hipMemsetAsync(flags, 0, 16384, stream);
  convert_weights<<<2048, 256, 0, stream>>>(w_ih, w_hh, h2h_w, out_w, b_ih, b_hh, wih_b, whh_b,
                                            h2hw_b, outw_b, bias_sum);

  const int nch = kS / CHUNK;
  for (int ci = 0; ci < nch; ++ci) {
    const long t0 = (long)ci * CHUNK;
    conv_pool<<<(int)(rowsC / 8), 256, 0, stream>>>(input_, conv_w, conv_b, feat_c, t0 * kB);
    gemm_bt_bf16<2><<<dim3((int)(rowsC / 128), kG / 128), 256, 0, stream>>>(
        feat_c, wih_b, bias_sum, xw_c, kG, kLIN);
    lstm_rec<<<RNB, 512, 0, stream>>>(xw_c, whh_b, hidden, cell, cstate, hbuf, hs_c, flags, CHUNK,
                                      ci == 0 ? 1 : 0, ci * (CHUNK + 1));
    gemm_bt_bf16<1><<<dim3((int)(rowsC / 128), kH / 128), 256, 0, stream>>>(
        hs_c, h2hw_b, h2h_b, h2_c, kH, kH);
    out_head<<<(int)(rowsC / 64), 256, 0, stream>>>(h2_c, outw_b, out_b, out + t0 * kB * kO);
  }
}

// Round 11
// 2848.369 us; speedup vs baseline: 3.4300x; 1.0086x over previous
//
#include <hip/hip_runtime.h>
#include <stdint.h>
#include <stddef.h>

// ---------------- problem constants ----------------
#define kS 512
#define kB 64
#define kD 120
#define kOC 16
#define kKSZ 6
#define kPOOL 114
#define kLIN 1824   // 16*114
#define kH 1024
#define kG 4096
#define kO 48
#define kROWS (kS * kB)  // 32768
#define RNB 256          // recurrence blocks: 64 unit-slices x 4 batch-quarters
#define SLOT 16384       // 8B chunks per h slot (64 writers x 256)

typedef __attribute__((ext_vector_type(8))) short bf16x8;
typedef __attribute__((ext_vector_type(4))) float f32x4;

__device__ __forceinline__ unsigned short f32_to_bf16(float f) {
  unsigned u = __float_as_uint(f);
  u += 0x7FFFu + ((u >> 16) & 1u);
  return (unsigned short)(u >> 16);
}
__device__ __forceinline__ float bf16_to_f32(unsigned short h) {
  return __uint_as_float(((unsigned)h) << 16);
}
__device__ __forceinline__ float sigmoid_(float x) { return 1.f / (1.f + __expf(-x)); }
__device__ __forceinline__ float tanh_(float x) { return 1.f - 2.f / (__expf(2.f * x) + 1.f); }

__device__ __forceinline__ void load_lds_16(const void* g, void* l) {
  __builtin_amdgcn_global_load_lds((__attribute__((address_space(1))) void*)g,
                                   (__attribute__((address_space(3))) void*)l, 16, 0, 0);
}

// relaxed agent-scope 8B ops: sc-coherent loads/stores at LLC, NO wbl2/inv
__device__ __forceinline__ unsigned long long coh_load(const unsigned long long* p) {
  return __hip_atomic_load(p, __ATOMIC_RELAXED, __HIP_MEMORY_SCOPE_AGENT);
}
__device__ __forceinline__ void coh_store(unsigned long long* p, unsigned long long v) {
  __hip_atomic_store(p, v, __ATOMIC_RELAXED, __HIP_MEMORY_SCOPE_AGENT);
}
// sentinel = memset 0x7F -> element0 bits[14:7] == 0xFE (impossible for |h|<1)
__device__ __forceinline__ bool inval(unsigned long long q) {
  return ((q >> 7) & 0xFFull) == 0xFEull;
}

// ---------------- K0: weight conversion ----------------
__global__ void convert_weights(const float* __restrict__ wih, const float* __restrict__ whh,
                                const float* __restrict__ h2hw, const float* __restrict__ outw,
                                const float* __restrict__ bih, const float* __restrict__ bhh,
                                unsigned short* __restrict__ wihb, unsigned short* __restrict__ whhb,
                                unsigned short* __restrict__ h2hwb, unsigned short* __restrict__ outwb,
                                float* __restrict__ bsum) {
  const size_t N0 = (size_t)kG * kLIN;
  const size_t N1 = (size_t)kG * kH;
  const size_t N2 = (size_t)kH * kH;
  const size_t N3 = (size_t)kO * kH;
  const size_t N4 = kG;
  const size_t TOT = N0 + N1 + N2 + N3 + N4;
  for (size_t i = (size_t)blockIdx.x * blockDim.x + threadIdx.x; i < TOT;
       i += (size_t)gridDim.x * blockDim.x) {
    if (i < N0) wihb[i] = f32_to_bf16(wih[i]);
    else if (i < N0 + N1) whhb[i - N0] = f32_to_bf16(whh[i - N0]);
    else if (i < N0 + N1 + N2) h2hwb[i - N0 - N1] = f32_to_bf16(h2hw[i - N0 - N1]);
    else if (i < N0 + N1 + N2 + N3) outwb[i - N0 - N1 - N2] = f32_to_bf16(outw[i - N0 - N1 - N2]);
    else { size_t j = i - N0 - N1 - N2 - N3; bsum[j] = bih[j] + bhh[j]; }
  }
}

// ---------------- K1: conv1d + relu + maxpool -> feat bf16 (per-chunk) ----------------
__global__ __launch_bounds__(256) void conv_pool(const float* __restrict__ x,
                                                 const float* __restrict__ cw,
                                                 const float* __restrict__ cb,
                                                 unsigned short* __restrict__ feat,
                                                 long row_base) {
  __shared__ float xs[8][kD];
  __shared__ float ws[kOC][kKSZ];
  __shared__ float bs[kOC];
  const int tid = threadIdx.x;
  const long grow0 = row_base + (long)blockIdx.x * 8;
  const long lrow0 = (long)blockIdx.x * 8;
  if (tid < kOC * kKSZ) ws[tid / kKSZ][tid % kKSZ] = cw[tid];
  if (tid < kOC) bs[tid] = cb[tid];
  for (int i = tid; i < 8 * kD; i += 256) xs[i / kD][i % kD] = x[grow0 * kD + i];
  __syncthreads();
  for (int r = 0; r < 8; ++r) {
    for (int idx = tid; idx < kLIN; idx += 256) {
      const int oc = idx / kPOOL, p = idx % kPOOL;
      float c0 = bs[oc], c1 = bs[oc];
#pragma unroll
      for (int k = 0; k < kKSZ; ++k) {
        c0 += xs[r][p + k] * ws[oc][k];
        c1 += xs[r][p + 1 + k] * ws[oc][k];
      }
      float v = fmaxf(fmaxf(c0, c1), 0.f);
      feat[(lrow0 + r) * kLIN + idx] = f32_to_bf16(v);
    }
  }
}

// ---------------- K2/K4: 128x128 bf16 MFMA GEMM ----------------
// MODE 0: C = A@B^T + bias (row-major). MODE 1: relu(...). MODE 2: no relu,
// C written in lstm-permuted layout: col=(g,ublk,ur) -> ((row*64+ublk)*64+g*16+ur)
template <int MODE>
__global__ __launch_bounds__(256) void gemm_bt_bf16(const unsigned short* __restrict__ A,
                                                    const unsigned short* __restrict__ B,
                                                    const float* __restrict__ bias,
                                                    unsigned short* __restrict__ C,
                                                    int N, int K) {
  __shared__ unsigned short Al[2][128 * 32];
  __shared__ unsigned short Bl[2][128 * 32];
  const int tid = threadIdx.x;
  const int lane = tid & 63;
  const int wid = tid >> 6;
  const int wm = wid >> 1, wn = wid & 1;
  const long bm = (long)blockIdx.x * 128;
  const long bn = (long)blockIdx.y * 128;
  const int NT = K / 32;

  f32x4 acc[4][4] = {};

  auto stage = [&](int buf, int kt) {
    const long k0 = (long)kt * 32;
#pragma unroll
    for (int rnd = 0; rnd < 2; ++rnd) {
      const int chunk = rnd * 256 + tid;  // 0..511
      const int r = chunk >> 2, c = chunk & 3;
      load_lds_16(A + (bm + r) * K + k0 + c * 8, &Al[buf][chunk * 8]);
      load_lds_16(B + (bn + r) * K + k0 + c * 8, &Bl[buf][chunk * 8]);
    }
  };

  stage(0, 0);
  __syncthreads();
  int buf = 0;
  for (int kt = 0; kt < NT; ++kt) {
    if (kt + 1 < NT) stage(buf ^ 1, kt + 1);
    bf16x8 af[4], bfr[4];
#pragma unroll
    for (int i = 0; i < 4; ++i) {
      const int ar = wm * 64 + i * 16 + (lane & 15);
      af[i] = *(const bf16x8*)&Al[buf][ar * 32 + (lane >> 4) * 8];
      const int bc = wn * 64 + i * 16 + (lane & 15);
      bfr[i] = *(const bf16x8*)&Bl[buf][bc * 32 + (lane >> 4) * 8];
    }
#pragma unroll
    for (int i = 0; i < 4; ++i)
#pragma unroll
      for (int j = 0; j < 4; ++j)
        acc[i][j] = __builtin_amdgcn_mfma_f32_16x16x32_bf16(af[i], bfr[j], acc[i][j], 0, 0, 0);
    __syncthreads();
    buf ^= 1;
  }

#pragma unroll
  for (int i = 0; i < 4; ++i) {
#pragma unroll
    for (int j = 0; j < 4; ++j) {
      const long col = bn + wn * 64 + j * 16 + (lane & 15);
      const float bv = bias[col];
#pragma unroll
      for (int e = 0; e < 4; ++e) {
        const long row = bm + wm * 64 + i * 16 + (lane >> 4) * 4 + e;
        float v = acc[i][j][e] + bv;
        if (MODE == 1) v = fmaxf(v, 0.f);
        if (MODE == 2) {
          const int g = (int)(col >> 10), ub = (int)((col >> 4) & 63), ur = (int)(col & 15);
          C[(row * 64 + ub) * 64 + g * 16 + ur] = f32_to_bf16(v);
        } else {
          C[row * N + col] = f32_to_bf16(v);
        }
      }
    }
  }
}

// ---------------- K3: persistent LSTM recurrence (per-chunk) ----------------
// 256 blocks x 512 thr, 1 block/CU. Block (ublk=bid&63, bqtr=bid>>6) owns
// 16 units x 16 batches; 8 waves split k 8-ways.
// DATA-AS-FLAG: hbuf has one fresh 128KB slot PER GLOBAL STEP (never reused,
// no WAR, no ordering needed). Slots pre-set to 0x7F7F (bf16 exp=0xFE,
// impossible for |h|<1) by a host-side memset captured in the graph.
// Consumers batch-issue 8 chunk loads, retry only chunks still sentinel.
// Producers: gates -> hstage(LDS, ushort) -> one 8B coh_store. No fences,
// no flags, no vmcnt drain - the data IS the message.
__global__ __launch_bounds__(512) void lstm_rec(const unsigned short* __restrict__ xw,
                                                const unsigned short* __restrict__ whh,
                                                const float* __restrict__ h0,
                                                const float* __restrict__ c0,
                                                float* __restrict__ cst,
                                                unsigned long long* __restrict__ hbuf,
                                                unsigned short* __restrict__ hs,
                                                int nsteps, int first, int t0step) {
  __shared__ unsigned short Bl[64 * 1024];     // 128 KB; idx = kc*512 + col*8 + e
  __shared__ unsigned short hstage[256];       // 512 B (16 batches x 16 units)
  __shared__ float pacc_f[7][4][4][64];        // 28 KB SoA partials (waves 1..7)
  const int tid = threadIdx.x;
  const int lane = tid & 63;
  const int kq = tid >> 6;   // wave = k-eighth
  const int urow = lane & 15;
  const int bq = lane >> 4;
  const int bid = blockIdx.x;
  const int ublk = bid & 63;
  const int bqtr = bid >> 6;
  const int u0 = ublk * 16;
  const int gb0 = bqtr * 16 + bq * 4;  // global batch base of C-frag (wave-0 gates)

  // stage W_hh slice (64 gate-cols x 1024 K) into LDS, k-tiled layout
  for (int idx = tid; idx < 64 * 128; idx += 512) {
    const int col = idx & 63;
    const int kc = idx >> 6;
    const int gcol = (col >> 4) * kH + u0 + (col & 15);
    *(bf16x8*)&Bl[kc * 512 + col * 8] = *(const bf16x8*)&whh[(long)gcol * kH + kc * 8];
  }
  float creg[4];
  if (first) {
    if (tid < 64) {  // publish slot-0 h quarter for this (ublk, bqtr)
      const int lb = tid >> 2, un4 = (tid & 3) * 4, gb = bqtr * 16 + lb;
      unsigned long long v = 0;
#pragma unroll
      for (int e = 0; e < 4; ++e) {
        const unsigned long long b16 = f32_to_bf16(h0[gb * kH + u0 + un4 + e]);
        v |= b16 << (16 * e);
      }
      coh_store(&hbuf[(size_t)ublk * 256 + gb * 4 + (tid & 3)], v);
    }
    if (kq == 0)
#pragma unroll
      for (int j = 0; j < 4; ++j) creg[j] = c0[(gb0 + j) * kH + u0 + urow];
  } else {
    if (kq == 0)
#pragma unroll
      for (int j = 0; j < 4; ++j) creg[j] = cst[(gb0 + j) * kH + u0 + urow];
  }
  __syncthreads();  // Bl staged

  // x-part of gates for step t (wave-0 only)
  float xv[4][4];
  auto load_xv = [&](int t, float (*dst)[4]) {
#pragma unroll
    for (int j = 0; j < 4; ++j) {
      const unsigned short* xp = xw + ((long)(t * kB + gb0 + j) * 64 + ublk) * 64 + urow;
#pragma unroll
      for (int g = 0; g < 4; ++g) dst[j][g] = bf16_to_f32(xp[g * 16]);
    }
  };
  if (kq == 0) load_xv(0, xv);

  // A-frag chunk offset in writer slot: batch = bqtr*16 + (lane&15)
  const int ach = (bqtr * 16 + urow) * 4 + (bq & 1) * 2;

  for (int t = 0; t < nsteps; ++t) {
    const unsigned long long* curs = hbuf + (size_t)(t0step + t) * SLOT;
    unsigned long long* nxts = hbuf + (size_t)(t0step + t + 1) * SLOT;

    // batched issue of all 8 chunk loads (one pipelined RTT), then retry
    unsigned long long q[8];
#pragma unroll
    for (int ktl = 0; ktl < 4; ++ktl) {
      const unsigned long long* src =
          curs + (size_t)((kq * 4 + ktl) * 2 + (bq >> 1)) * 256 + ach;
      q[2 * ktl] = coh_load(src);
      q[2 * ktl + 1] = coh_load(src + 1);
    }
#pragma unroll
    for (int ktl = 0; ktl < 4; ++ktl) {
      const unsigned long long* src =
          curs + (size_t)((kq * 4 + ktl) * 2 + (bq >> 1)) * 256 + ach;
      while (inval(q[2 * ktl])) q[2 * ktl] = coh_load(src);
      while (inval(q[2 * ktl + 1])) q[2 * ktl + 1] = coh_load(src + 1);
    }

    f32x4 acc[4] = {};
#pragma unroll
    for (int ktl = 0; ktl < 4; ++ktl) {
      union { unsigned long long qq[2]; bf16x8 v; } a;
      a.qq[0] = q[2 * ktl];
      a.qq[1] = q[2 * ktl + 1];
      const int kc = (kq * 4 + ktl) * 4 + bq;
#pragma unroll
      for (int g = 0; g < 4; ++g) {
        const bf16x8 bb = *(const bf16x8*)&Bl[kc * 512 + (g * 16 + urow) * 8];
        acc[g] = __builtin_amdgcn_mfma_f32_16x16x32_bf16(a.v, bb, acc[g], 0, 0, 0);
      }
    }

    if (kq != 0) {
#pragma unroll
      for (int g = 0; g < 4; ++g)
#pragma unroll
        for (int j = 0; j < 4; ++j) pacc_f[kq - 1][g][j][lane] = acc[g][j];
    }
    __syncthreads();  // partials ready

    unsigned long long qpub = 0;
    if (kq == 0) {
#pragma unroll
      for (int j = 0; j < 4; ++j) {
        float s[4];
#pragma unroll
        for (int g = 0; g < 4; ++g) {
          float sum = acc[g][j] + xv[j][g];
#pragma unroll
          for (int p = 0; p < 7; ++p) sum += pacc_f[p][g][j][lane];
          s[g] = sum;
        }
        const float gi = sigmoid_(s[0]);
        const float gf = sigmoid_(s[1]);
        const float gg = tanh_(s[2]);
        const float go = sigmoid_(s[3]);
        creg[j] = gf * creg[j] + gi * gg;
        hstage[(bq * 4 + j) * 16 + urow] = f32_to_bf16(go * tanh_(creg[j]));
      }
      // transpose via LDS (same-type ushort accesses -> compiler-ordered),
      // publish immediately: the store IS the synchronization
      asm volatile("" ::: "memory");
#pragma unroll
      for (int e = 0; e < 4; ++e)
        qpub |= ((unsigned long long)hstage[(lane >> 2) * 16 + (lane & 3) * 4 + e]) << (16 * e);
      coh_store(&nxts[(size_t)ublk * 256 + (bqtr * 16 + (lane >> 2)) * 4 + (lane & 3)], qpub);
    }
    __syncthreads();  // pacc consumed; waves 1-7 run ahead to next poll

    if (kq == 0) {
      // off critical path: hs relu-store + next-step xw prefetch
      unsigned long long r = 0;
#pragma unroll
      for (int e = 0; e < 4; ++e) {
        unsigned long long s = (qpub >> (16 * e)) & 0xFFFFull;
        if (s & 0x8000ull) s = 0;
        r |= s << (16 * e);
      }
      const int lb = lane >> 2, un4 = (lane & 3) * 4, gb = bqtr * 16 + lb;
      *(unsigned long long*)&hs[(long)(t * kB + gb) * kH + u0 + un4] = r;
      if (t + 1 < nsteps) load_xv(t + 1, xv);
    }
  }

  if (kq == 0)
#pragma unroll
    for (int j = 0; j < 4; ++j) cst[(gb0 + j) * kH + u0 + urow] = creg[j];
}

// ---------------- K5: output head + log_softmax (per-chunk) ----------------
__global__ __launch_bounds__(256) void out_head(const unsigned short* __restrict__ h2,
                                                const unsigned short* __restrict__ ow,
                                                const float* __restrict__ ob,
                                                float* __restrict__ out) {
  __shared__ unsigned short Wl[48 * 1024];  // 96 KB; idx = kc*384 + col*8 + e
  const int tid = threadIdx.x;
  const int lane = tid & 63;
  const int w = tid >> 6;
  for (int idx = tid; idx < 48 * 128; idx += 256) {
    const int col = idx % 48;
    const int kc = idx / 48;
    *(bf16x8*)&Wl[kc * 384 + col * 8] = *(const bf16x8*)&ow[(long)col * kH + kc * 8];
  }
  __syncthreads();
  const long row0 = (long)blockIdx.x * 64 + w * 16;
  f32x4 acc[3] = {};
  const unsigned short* arow = h2 + (row0 + (lane & 15)) * kH + (lane >> 4) * 8;
#pragma unroll 8
  for (int kt = 0; kt < 32; ++kt) {
    const bf16x8 a = *(const bf16x8*)(arow + kt * 32);
    const int kc = kt * 4 + (lane >> 4);
#pragma unroll
    for (int n = 0; n < 3; ++n) {
      const bf16x8 bb = *(const bf16x8*)&Wl[kc * 384 + (n * 16 + (lane & 15)) * 8];
      acc[n] = __builtin_amdgcn_mfma_f32_16x16x32_bf16(a, bb, acc[n], 0, 0, 0);
    }
  }
  const int colb = lane & 15;
#pragma unroll
  for (int j = 0; j < 4; ++j) {
    float v[3];
#pragma unroll
    for (int n = 0; n < 3; ++n) v[n] = acc[n][j] + ob[n * 16 + colb];
    float m = fmaxf(fmaxf(v[0], v[1]), v[2]);
#pragma unroll
    for (int s = 1; s < 16; s <<= 1) m = fmaxf(m, __shfl_xor(m, s, 64));
    float se = __expf(v[0] - m) + __expf(v[1] - m) + __expf(v[2] - m);
#pragma unroll
    for (int s = 1; s < 16; s <<= 1) se += __shfl_xor(se, s, 64);
    const float lse = m + __logf(se);
    const long row = row0 + (lane >> 4) * 4 + j;
#pragma unroll
    for (int n = 0; n < 3; ++n) out[row * 48 + n * 16 + colb] = v[n] - lse;
  }
}

// ---------------- host ----------------
extern "C" void kernel_launch(void* const* d_in, const int* in_sizes, int n_in,
                              void* d_out, int out_size, void* d_ws, size_t ws_size,
                              hipStream_t stream) {
  const float* input_ = (const float*)d_in[0];
  const float* hidden = (const float*)d_in[1];
  const float* cell = (const float*)d_in[2];
  const float* conv_w = (const float*)d_in[3];
  const float* conv_b = (const float*)d_in[4];
  const float* w_ih = (const float*)d_in[5];
  const float* w_hh = (const float*)d_in[6];
  const float* b_ih = (const float*)d_in[7];
  const float* b_hh = (const float*)d_in[8];
  const float* h2h_w = (const float*)d_in[9];
  const float* h2h_b = (const float*)d_in[10];
  const float* out_w = (const float*)d_in[11];
  const float* out_b = (const float*)d_in[12];
  float* out = (float*)d_out;

  const size_t HBUF_BYTES = (size_t)(kS + 1) * SLOT * 8;  // 67.2 MB, one slot/step

  // fixed (chunk-independent) footprint
  const size_t FIXED = ((size_t)kG * kLIN + (size_t)kG * kH + (size_t)kH * kH +
                        (size_t)kO * kH) * 2 +
                       (size_t)kG * 4 +
                       HBUF_BYTES +
                       (size_t)kB * kH * 4 +
                       16 * 256;

  // largest chunk (timesteps) whose working set fits ws
  int CHUNK = 2;
  const int cand[] = {512, 256, 128, 64, 32, 16, 8, 4, 2};
  for (int i = 0; i < 9; ++i) {
    const size_t rowsC = (size_t)cand[i] * kB;
    const size_t need = FIXED + rowsC * (kLIN + kG) * 2;
    if (need <= ws_size) { CHUNK = cand[i]; break; }
  }
  const size_t rowsC = (size_t)CHUNK * kB;

  char* ws = (char*)d_ws;
  size_t off = 0;
  auto alloc = [&](size_t bytes) {
    char* p = ws + off;
    off += (bytes + 255) & ~(size_t)255;
    return p;
  };
  unsigned short* regionA = (unsigned short*)alloc(rowsC * kLIN * 2);
  unsigned short* regionB = (unsigned short*)alloc(rowsC * kG * 2);
  unsigned short* wih_b = (unsigned short*)alloc((size_t)kG * kLIN * 2);
  unsigned short* whh_b = (unsigned short*)alloc((size_t)kG * kH * 2);
  unsigned short* h2hw_b = (unsigned short*)alloc((size_t)kH * kH * 2);
  unsigned short* outw_b = (unsigned short*)alloc((size_t)kO * kH * 2);
  float* bias_sum = (float*)alloc((size_t)kG * 4);
  unsigned long long* hbuf = (unsigned long long*)alloc(HBUF_BYTES);
  float* cstate = (float*)alloc((size_t)kB * kH * 4);

  unsigned short* feat_c = regionA;
  unsigned short* hs_c = regionA;   // feat dead after gemm<2>
  unsigned short* xw_c = regionB;
  unsigned short* h2_c = regionB;   // xw dead after lstm_rec

  // sentinel-init all h slots (0x7F7F = bf16 exp 0xFE, impossible for |h|<1).
  // Captured in the graph -> re-runs every replay.
  hipMemsetAsync(hbuf, 0x7F, HBUF_BYTES, stream);
  convert_weights<<<2048, 256, 0, stream>>>(w_ih, w_hh, h2h_w, out_w, b_ih, b_hh, wih_b, whh_b,
                                            h2hw_b, outw_b, bias_sum);

  const int nch = kS / CHUNK;
  for (int ci = 0; ci < nch; ++ci) {
    const long t0 = (long)ci * CHUNK;
    conv_pool<<<(int)(rowsC / 8), 256, 0, stream>>>(input_, conv_w, conv_b, feat_c, t0 * kB);
    gemm_bt_bf16<2><<<dim3((int)(rowsC / 128), kG / 128), 256, 0, stream>>>(
        feat_c, wih_b, bias_sum, xw_c, kG, kLIN);
    lstm_rec<<<RNB, 512, 0, stream>>>(xw_c, whh_b, hidden, cell, cstate, hbuf, hs_c, CHUNK,
                                      ci == 0 ? 1 : 0, (int)t0);
    gemm_bt_bf16<1><<<dim3((int)(rowsC / 128), kH / 128), 256, 0, stream>>>(
        hs_c, h2hw_b, h2h_b, h2_c, kH, kH);
    out_head<<<(int)(rowsC / 64), 256, 0, stream>>>(h2_c, outw_b, out_b, out + t0 * kB * kO);
  }
}